// Round 2
// baseline (6906.045 us; speedup 1.0000x reference)
//
#include <hip/hip_runtime.h>

// ---------------- GEMM fp32: C[M,N] = A[M,K] @ B[K,N] + bias[N], optional relu.
// M % 64 == 0, N % 64 == 0, K % 16 == 0. Block 256 threads, 64x64 tile, 4x4/thread.
__global__ __launch_bounds__(256) void gemm_f32(
    const float* __restrict__ A, const float* __restrict__ B,
    const float* __restrict__ bias, float* __restrict__ C,
    int M, int N, int K, int relu)
{
  __shared__ float As[16][68];
  __shared__ float Bs[16][68];
  int tid = threadIdx.x;
  int bn0 = blockIdx.x * 64;
  long bm0 = (long)blockIdx.y * 64;
  int tx = tid & 15, ty = tid >> 4;
  int am = tid >> 2, ak = (tid & 3) * 4;   // A loader: row am, k-quad ak
  int bk = tid >> 4, bn = (tid & 15) * 4;  // B loader: k row bk, col-quad bn
  float acc[4][4];
#pragma unroll
  for (int i = 0; i < 4; ++i)
#pragma unroll
    for (int j = 0; j < 4; ++j) acc[i][j] = 0.f;

  for (int k0 = 0; k0 < K; k0 += 16) {
    float4 av = *(const float4*)&A[(bm0 + am) * (long)K + k0 + ak];
    float4 bv = *(const float4*)&B[(long)(k0 + bk) * N + bn0 + bn];
    __syncthreads();
    As[ak + 0][am] = av.x;
    As[ak + 1][am] = av.y;
    As[ak + 2][am] = av.z;
    As[ak + 3][am] = av.w;
    *(float4*)&Bs[bk][bn] = bv;
    __syncthreads();
#pragma unroll
    for (int k = 0; k < 16; ++k) {
      float4 a4 = *(const float4*)&As[k][ty * 4];
      float4 b4 = *(const float4*)&Bs[k][tx * 4];
      float ar[4] = {a4.x, a4.y, a4.z, a4.w};
      float br[4] = {b4.x, b4.y, b4.z, b4.w};
#pragma unroll
      for (int i = 0; i < 4; ++i)
#pragma unroll
        for (int j = 0; j < 4; ++j) acc[i][j] += ar[i] * br[j];
    }
  }
  float4 bb = *(const float4*)&bias[bn0 + tx * 4];
  float br[4] = {bb.x, bb.y, bb.z, bb.w};
#pragma unroll
  for (int i = 0; i < 4; ++i) {
    float4 o;
    o.x = acc[i][0] + br[0];
    o.y = acc[i][1] + br[1];
    o.z = acc[i][2] + br[2];
    o.w = acc[i][3] + br[3];
    if (relu) {
      o.x = fmaxf(o.x, 0.f); o.y = fmaxf(o.y, 0.f);
      o.z = fmaxf(o.z, 0.f); o.w = fmaxf(o.w, 0.f);
    }
    *(float4*)&C[(bm0 + ty * 4 + i) * (long)N + bn0 + tx * 4] = o;
  }
}

// ---------------- Fused attention, one block per (row-block, head).
// All Q/K/V/O row-major [rows, 512], feature = n*64 + h.
// mode_ca=0: Q,K,V,O all chunk-local; block-row rl = idx>>3.
// mode_ca=1: O chunk-local at rl; global row-block g = rb0+rl encodes a*32+b;
//            K/V from 1024-row global buffer at batch a = g>>5;
//            Q chunk-local at (l0 ? g&31 : rl).
__global__ __launch_bounds__(256) void attn_f32(
    const float* __restrict__ Qp, const float* __restrict__ Kp,
    const float* __restrict__ Vp, float* __restrict__ Op,
    int mode_ca, int l0, int rb0)
{
  __shared__ float Ks[128][68];
  __shared__ float Qs[32][68];
  __shared__ float Ss[32][132];
  __shared__ float rsum[32];
  int idx = blockIdx.x;
  int n = idx & 7;
  int rl = idx >> 3;
  long qbase, kbase, obase;
  obase = (long)rl * 128 * 512 + n * 64;
  if (!mode_ca) {
    qbase = obase; kbase = obase;
  } else {
    int g = rb0 + rl;
    int a = g >> 5;
    int qblk = l0 ? (g & 31) : rl;
    qbase = (long)qblk * 128 * 512 + n * 64;
    kbase = (long)a * 128 * 512 + n * 64;
  }
  int tid = threadIdx.x;
#pragma unroll
  for (int i = 0; i < 32; ++i) {
    int e = tid + i * 256;
    Ks[e >> 6][e & 63] = Kp[kbase + (long)(e >> 6) * 512 + (e & 63)];
  }
  int r = tid >> 3, c0 = tid & 7;
  int hlane = tid & 63, rg = tid >> 6;
  for (int ch = 0; ch < 4; ++ch) {
    __syncthreads();  // Ks ready (ch=0); prior chunk fully consumed (ch>0)
#pragma unroll
    for (int i = 0; i < 8; ++i) {
      int e = tid + i * 256;
      Qs[e >> 6][e & 63] = Qp[qbase + (long)(ch * 32 + (e >> 6)) * 512 + (e & 63)];
    }
    __syncthreads();
    // scores: thread owns row r, cols c0 + 8j
    float acc[16];
#pragma unroll
    for (int j = 0; j < 16; ++j) acc[j] = 0.f;
    for (int h = 0; h < 64; h += 4) {
      float4 qv = *(const float4*)&Qs[r][h];
#pragma unroll
      for (int j = 0; j < 16; ++j) {
        float4 kv = *(const float4*)&Ks[c0 + j * 8][h];
        acc[j] += qv.x * kv.x + qv.y * kv.y + qv.z * kv.z + qv.w * kv.w;
      }
    }
    float mx = -1e30f;
#pragma unroll
    for (int j = 0; j < 16; ++j) { acc[j] *= 0.125f; mx = fmaxf(mx, acc[j]); }
#pragma unroll
    for (int off = 1; off < 8; off <<= 1) mx = fmaxf(mx, __shfl_xor(mx, off));
    float sum = 0.f;
#pragma unroll
    for (int j = 0; j < 16; ++j) { acc[j] = __expf(acc[j] - mx); sum += acc[j]; }
#pragma unroll
    for (int off = 1; off < 8; off <<= 1) sum += __shfl_xor(sum, off);
#pragma unroll
    for (int j = 0; j < 16; ++j) Ss[r][c0 + 8 * j] = acc[j];
    if (c0 == 0) rsum[r] = sum;
    __syncthreads();
    // PV: thread owns column hlane, rows rg + 4i; V streamed from global (L1/L2-resident)
    float ov[8];
#pragma unroll
    for (int i = 0; i < 8; ++i) ov[i] = 0.f;
    for (int k = 0; k < 128; ++k) {
      float v = Vp[kbase + (long)k * 512 + hlane];
#pragma unroll
      for (int i = 0; i < 8; ++i) ov[i] += Ss[rg + 4 * i][k] * v;
    }
#pragma unroll
    for (int i = 0; i < 8; ++i) {
      int rr = rg + 4 * i;
      Op[obase + (long)(ch * 32 + rr) * 512 + hlane] = ov[i] / rsum[rr];
    }
  }
}

// ---------------- Residual + LayerNorm over rows of 512. One wave per row.
// out row = row0 + local; xin row = (row0+local) & bmask; add indexed chunk-local.
__global__ __launch_bounds__(256) void ln_f32(
    const float* __restrict__ xin, const float* __restrict__ add,
    float* __restrict__ out, const float* __restrict__ g,
    const float* __restrict__ bt, long row0, int bmask)
{
  int rl = blockIdx.x * 4 + (threadIdx.x >> 6);
  long row = row0 + rl;
  int lane = threadIdx.x & 63;
  long xr = (row & (long)bmask) * 512 + lane * 8;
  float4 v0 = *(const float4*)&xin[xr];
  float4 v1 = *(const float4*)&xin[xr + 4];
  if (add) {
    long ar = (long)rl * 512 + lane * 8;
    float4 a0 = *(const float4*)&add[ar];
    float4 a1 = *(const float4*)&add[ar + 4];
    v0.x += a0.x; v0.y += a0.y; v0.z += a0.z; v0.w += a0.w;
    v1.x += a1.x; v1.y += a1.y; v1.z += a1.z; v1.w += a1.w;
  }
  float s = v0.x + v0.y + v0.z + v0.w + v1.x + v1.y + v1.z + v1.w;
  float sq = v0.x * v0.x + v0.y * v0.y + v0.z * v0.z + v0.w * v0.w
           + v1.x * v1.x + v1.y * v1.y + v1.z * v1.z + v1.w * v1.w;
#pragma unroll
  for (int off = 1; off < 64; off <<= 1) {
    s += __shfl_xor(s, off);
    sq += __shfl_xor(sq, off);
  }
  float mean = s * (1.f / 512.f);
  float var = sq * (1.f / 512.f) - mean * mean;
  float rst = rsqrtf(var + 1e-6f);
  int c = lane * 8;
  float4 g0 = *(const float4*)&g[c], g1 = *(const float4*)&g[c + 4];
  float4 b0 = *(const float4*)&bt[c], b1 = *(const float4*)&bt[c + 4];
  float4 o0, o1;
  o0.x = (v0.x - mean) * rst * g0.x + b0.x;
  o0.y = (v0.y - mean) * rst * g0.y + b0.y;
  o0.z = (v0.z - mean) * rst * g0.z + b0.z;
  o0.w = (v0.w - mean) * rst * g0.w + b0.w;
  o1.x = (v1.x - mean) * rst * g1.x + b1.x;
  o1.y = (v1.y - mean) * rst * g1.y + b1.y;
  o1.z = (v1.z - mean) * rst * g1.z + b1.z;
  o1.w = (v1.w - mean) * rst * g1.w + b1.w;
  long orow = row * 512 + c;
  *(float4*)&out[orow] = o0;
  *(float4*)&out[orow + 4] = o1;
}

// ---------------- wo (L,N,D,H) -> wo_t (L, N*H, D)
__global__ void transpose_wo_kernel(const float* __restrict__ wo, float* __restrict__ wt)
{
  int idx = blockIdx.x * 256 + threadIdx.x;  // 2*512*512 total
  if (idx >= 2 * 512 * 512) return;
  int l = idx >> 18;
  int rem = idx & 262143;
  int j = rem >> 9;   // n*64+h
  int d = rem & 511;
  int n = j >> 6, h = j & 63;
  wt[idx] = wo[(((long)l * 8 + n) * 512 + d) * 64 + h];
}

// ---------------- mean over tokens 1..127 of [ab, 128, 512] -> [ab, 512]
__global__ void pool_mean(const float* __restrict__ X, float* __restrict__ P)
{
  int ab = blockIdx.x;
  for (int dd = threadIdx.x; dd < 512; dd += 256) {
    const float* base = X + (long)ab * 128 * 512 + dd;
    float sacc = 0.f;
    for (int t = 1; t < 128; ++t) sacc += base[t * 512];
    P[ab * 512 + dd] = sacc * (1.f / 127.f);
  }
}

// ---------------- qf = qp @ Wq + bq, normalized -> QN (8 x 256)
__global__ void featq_kernel(const float* __restrict__ QP, const float* __restrict__ W,
                             const float* __restrict__ bias, float* __restrict__ QN)
{
  int a = blockIdx.x;
  int f = threadIdx.x;
  float acc = bias[f];
  const float* xr = QP + a * 512;
  for (int d = 0; d < 512; ++d) acc += xr[d] * W[d * 256 + f];
  __shared__ float red[256];
  red[f] = acc * acc;
  __syncthreads();
  for (int s = 128; s > 0; s >>= 1) {
    if (f < s) red[f] += red[f + s];
    __syncthreads();
  }
  float rn = rsqrtf(fmaxf(red[0], 1e-12f));
  QN[a * 256 + f] = acc * rn;
}

// ---------------- cf = cp @ Wc + bc, normalized, dotted against QN -> out (8*32)
__global__ void featc_kernel(const float* __restrict__ CP, const float* __restrict__ W,
                             const float* __restrict__ bias, const float* __restrict__ QN,
                             float* __restrict__ out)
{
  int ab = blockIdx.x;
  int f = threadIdx.x;
  float acc = bias[f];
  const float* xr = CP + ab * 512;
  for (int d = 0; d < 512; ++d) acc += xr[d] * W[d * 256 + f];
  __shared__ float red[256];
  red[f] = acc * acc;
  __syncthreads();
  for (int s = 128; s > 0; s >>= 1) {
    if (f < s) red[f] += red[f + s];
    __syncthreads();
  }
  float rn = rsqrtf(fmaxf(red[0], 1e-12f));
  float v = acc * rn * QN[(ab >> 5) * 256 + f];
  __syncthreads();
  red[f] = v;
  __syncthreads();
  for (int s = 128; s > 0; s >>= 1) {
    if (f < s) red[f] += red[f + s];
    __syncthreads();
  }
  if (f == 0) out[ab] = red[0];
}

extern "C" void kernel_launch(void* const* d_in, const int* in_sizes, int n_in,
                              void* d_out, int out_size, void* d_ws, size_t ws_size,
                              hipStream_t stream)
{
  (void)in_sizes; (void)n_in; (void)out_size;
  const float* c_in  = (const float*)d_in[0];
  const float* q_in  = (const float*)d_in[1];
  const float* sa_wq = (const float*)d_in[2];
  const float* sa_bq = (const float*)d_in[3];
  const float* sa_wk = (const float*)d_in[4];
  const float* sa_bk = (const float*)d_in[5];
  const float* sa_wv = (const float*)d_in[6];
  const float* sa_bv = (const float*)d_in[7];
  const float* sa_wo = (const float*)d_in[8];
  const float* sa_bo = (const float*)d_in[9];
  const float* ca_wq = (const float*)d_in[10];
  const float* ca_bq = (const float*)d_in[11];
  const float* ca_wk = (const float*)d_in[12];
  const float* ca_bk = (const float*)d_in[13];
  const float* ca_wv = (const float*)d_in[14];
  const float* ca_bv = (const float*)d_in[15];
  const float* ca_wo = (const float*)d_in[16];
  const float* ca_bo = (const float*)d_in[17];
  const float* ln1_g = (const float*)d_in[18];
  const float* ln1_b = (const float*)d_in[19];
  const float* ln2_g = (const float*)d_in[20];
  const float* ln2_b = (const float*)d_in[21];
  const float* ln3_g = (const float*)d_in[22];
  const float* ln3_b = (const float*)d_in[23];
  const float* ffn_w1 = (const float*)d_in[24];
  const float* ffn_b1 = (const float*)d_in[25];
  const float* ffn_w2 = (const float*)d_in[26];
  const float* ffn_b2 = (const float*)d_in[27];
  const float* lnf_g  = (const float*)d_in[28];
  const float* lnf_b  = (const float*)d_in[29];
  const float* feat_wq = (const float*)d_in[30];
  const float* feat_bq = (const float*)d_in[31];
  const float* feat_wc = (const float*)d_in[32];
  const float* feat_bc = (const float*)d_in[33];

  // ---- workspace layout (floats), ws_size-adaptive chunk size R
  float* ws = (float*)d_ws;
  float* X  = ws;                    // 32768 x 512   (16,777,216)
  float* Xs = X  + 16777216L;        //  4096 x 512   ( 2,097,152)
  float* WT = Xs + 2097152L;         //  2 layers x 2 proj-w^T (1,048,576)
  float* K0 = WT + 1048576L;         //  1024 x 512   (   524,288)
  float* V0 = K0 + 524288L;          //  1024 x 512   (   524,288)
  float* CP = V0 + 524288L;          //   256 x 512   (   131,072)
  float* QP = CP + 131072L;          //     8 x 512
  float* QN = QP + 4096L;            //     8 x 256
  const long base_fixed = 16777216L + 2097152L + 1048576L + 524288L + 524288L
                        + 131072L + 4096L + 2048L;   // 21,108,736 floats
  long availf = (long)(ws_size / 4) - base_fixed;
  long R = 4096;
  if (availf >= 2560L * 32768) R = 32768;
  else if (availf >= 2560L * 16384) R = 16384;
  else if (availf >= 2560L * 8192) R = 8192;
  float* Qc = ws + base_fixed;       // R x 512
  float* Kc = Qc + R * 512;          // R x 512   } FFN hidden (R/2 x 2048)
  float* Vc = Kc + R * 512;          // R x 512   } aliases Kc..Vc
  float* Oc = Vc + R * 512;          // R x 512
  float* Ac = Oc + R * 512;          // R x 512
  float* Hb = Kc;                    // FFN hidden buffer alias
  const long Rh = R / 2;             // FFN sub-chunk rows

  hipMemcpyAsync(Xs, c_in, (size_t)4096 * 512 * sizeof(float),
                 hipMemcpyDeviceToDevice, stream);
  transpose_wo_kernel<<<2048, 256, 0, stream>>>(sa_wo, WT);
  transpose_wo_kernel<<<2048, 256, 0, stream>>>(ca_wo, WT + 524288);

  // =================== layer 0 (x = Xs, 4096 rows) ===================
  {
    dim3 g4k(8, 64);
    gemm_f32<<<g4k, 256, 0, stream>>>(Xs, sa_wq, sa_bq, Qc, 4096, 512, 512, 0);
    gemm_f32<<<g4k, 256, 0, stream>>>(Xs, sa_wk, sa_bk, Kc, 4096, 512, 512, 0);
    gemm_f32<<<g4k, 256, 0, stream>>>(Xs, sa_wv, sa_bv, Vc, 4096, 512, 512, 0);
    attn_f32<<<32 * 8, 256, 0, stream>>>(Qc, Kc, Vc, Oc, 0, 0, 0);
    gemm_f32<<<g4k, 256, 0, stream>>>(Oc, WT, sa_bo, Ac, 4096, 512, 512, 0);
    ln_f32<<<1024, 256, 0, stream>>>(Xs, Ac, Xs, ln1_g, ln1_b, 0, 0x7FFFFFFF);
    // cross-attention: Q from Xs (all 32 b-blocks), K/V from q_in
    gemm_f32<<<g4k, 256, 0, stream>>>(Xs, ca_wq, ca_bq, Qc, 4096, 512, 512, 0);
    gemm_f32<<<dim3(8, 16), 256, 0, stream>>>(q_in, ca_wk, ca_bk, K0, 1024, 512, 512, 0);
    gemm_f32<<<dim3(8, 16), 256, 0, stream>>>(q_in, ca_wv, ca_bv, V0, 1024, 512, 512, 0);
    for (long c = 0; c < 32768; c += R) {
      attn_f32<<<(R / 128) * 8, 256, 0, stream>>>(Qc, K0, V0, Oc, 1, 1, (int)(c / 128));
      gemm_f32<<<dim3(8, R / 64), 256, 0, stream>>>(Oc, WT + 524288, ca_bo, Ac,
                                                    (int)R, 512, 512, 0);
      ln_f32<<<R / 4, 256, 0, stream>>>(Xs, Ac, X, ln2_g, ln2_b, c, 4095);
      for (long s = 0; s < R; s += Rh) {
        gemm_f32<<<dim3(32, Rh / 64), 256, 0, stream>>>(X + (c + s) * 512, ffn_w1,
                                                        ffn_b1, Hb, (int)Rh, 2048, 512, 1);
        gemm_f32<<<dim3(8, Rh / 64), 256, 0, stream>>>(Hb, ffn_w2, ffn_b2,
                                                       Ac + s * 512, (int)Rh, 512, 2048, 0);
      }
      ln_f32<<<R / 4, 256, 0, stream>>>(X, Ac, X, ln3_g, ln3_b, c, 0x7FFFFFFF);
    }
  }
  // =================== layer 1 (x = X, 32768 rows) ===================
  {
    gemm_f32<<<dim3(8, 16), 256, 0, stream>>>(q_in, ca_wk + 262144, ca_bk + 512,
                                              K0, 1024, 512, 512, 0);
    gemm_f32<<<dim3(8, 16), 256, 0, stream>>>(q_in, ca_wv + 262144, ca_bv + 512,
                                              V0, 1024, 512, 512, 0);
    dim3 gR(8, R / 64);
    for (long c = 0; c < 32768; c += R) {
      float* Xc = X + c * 512;
      gemm_f32<<<gR, 256, 0, stream>>>(Xc, sa_wq + 262144, sa_bq + 512, Qc, (int)R, 512, 512, 0);
      gemm_f32<<<gR, 256, 0, stream>>>(Xc, sa_wk + 262144, sa_bk + 512, Kc, (int)R, 512, 512, 0);
      gemm_f32<<<gR, 256, 0, stream>>>(Xc, sa_wv + 262144, sa_bv + 512, Vc, (int)R, 512, 512, 0);
      attn_f32<<<(R / 128) * 8, 256, 0, stream>>>(Qc, Kc, Vc, Oc, 0, 0, 0);
      gemm_f32<<<gR, 256, 0, stream>>>(Oc, WT + 262144, sa_bo + 512, Ac, (int)R, 512, 512, 0);
      ln_f32<<<R / 4, 256, 0, stream>>>(X, Ac, X, ln1_g + 512, ln1_b + 512, c, 0x7FFFFFFF);
      gemm_f32<<<gR, 256, 0, stream>>>(Xc, ca_wq + 262144, ca_bq + 512, Qc, (int)R, 512, 512, 0);
      attn_f32<<<(R / 128) * 8, 256, 0, stream>>>(Qc, K0, V0, Oc, 1, 0, (int)(c / 128));
      gemm_f32<<<gR, 256, 0, stream>>>(Oc, WT + 524288 + 262144, ca_bo + 512, Ac,
                                       (int)R, 512, 512, 0);
      ln_f32<<<R / 4, 256, 0, stream>>>(X, Ac, X, ln2_g + 512, ln2_b + 512, c, 0x7FFFFFFF);
      for (long s = 0; s < R; s += Rh) {
        gemm_f32<<<dim3(32, Rh / 64), 256, 0, stream>>>(X + (c + s) * 512, ffn_w1 + 1048576,
                                                        ffn_b1 + 2048, Hb, (int)Rh, 2048, 512, 1);
        gemm_f32<<<dim3(8, Rh / 64), 256, 0, stream>>>(Hb, ffn_w2 + 1048576, ffn_b2 + 512,
                                                       Ac + s * 512, (int)Rh, 512, 2048, 0);
      }
      ln_f32<<<R / 4, 256, 0, stream>>>(X, Ac, X, ln3_g + 512, ln3_b + 512, c, 0x7FFFFFFF);
    }
  }
  // =================== final LN + pooling + features + cosine ===================
  ln_f32<<<8192, 256, 0, stream>>>(X, nullptr, X, lnf_g, lnf_b, 0, 0x7FFFFFFF);
  pool_mean<<<256, 256, 0, stream>>>(X, CP);
  pool_mean<<<8, 256, 0, stream>>>(q_in, QP);
  featq_kernel<<<8, 256, 0, stream>>>(QP, feat_wq, feat_bq, QN);
  featc_kernel<<<256, 256, 0, stream>>>(CP, feat_wc, feat_bc, QN, (float*)d_out);
}

// Round 3
// 2406.642 us; speedup vs baseline: 2.8696x; 2.8696x over previous
//
#include <hip/hip_runtime.h>

using half8  = __attribute__((ext_vector_type(8))) _Float16;
using floatx4 = __attribute__((ext_vector_type(4))) float;

// ---------------- MFMA fp16 GEMM: C[M,N] = A[M,K] @ Bt[N,K]^T + bias[N]
// A fp16 [M][K], Bt fp16 [N][K] (pre-transposed), C fp32 or fp16 per flags.
// flags: bit0 = relu, bit1 = fp16 output. M%128==0, N%128==0, K%32==0.
// Block 256 threads = 4 waves; 128x128 tile; wave = 64x64 via 4x4 MFMA 16x16x32.
__global__ __launch_bounds__(256) void gemm_h(
    const _Float16* __restrict__ A, const _Float16* __restrict__ Bt,
    const float* __restrict__ bias, void* __restrict__ C,
    int M, int N, int K, int flags)
{
  __shared__ _Float16 As[128 * 40];   // row stride 40 halfs (80B) kills 8-way conflicts
  __shared__ _Float16 Bs[128 * 40];
  int tid = threadIdx.x;
  int lane = tid & 63, wave = tid >> 6;
  long bm0 = (long)blockIdx.y * 128;
  int bn0 = blockIdx.x * 128;
  int wm = (wave & 1) * 64, wn = (wave >> 1) * 64;
  int r0 = tid >> 2, kq = tid & 3;   // staging: thread covers rows r0 and r0+64, k-quad kq
  const _Float16* Ar0 = A + (bm0 + r0) * (long)K + kq * 8;
  const _Float16* Ar1 = Ar0 + 64 * (long)K;
  const _Float16* Br0 = Bt + (bn0 + r0) * (long)K + kq * 8;
  const _Float16* Br1 = Br0 + 64 * (long)K;
  int ls0 = r0 * 40 + kq * 8, ls1 = ls0 + 64 * 40;
  int mrow = lane & 15, quad = lane >> 4;
  floatx4 acc[4][4];
#pragma unroll
  for (int i = 0; i < 4; ++i)
#pragma unroll
    for (int j = 0; j < 4; ++j) acc[i][j] = (floatx4){0.f, 0.f, 0.f, 0.f};

  for (int kt = 0; kt < K; kt += 32) {
    uint4 a0 = *(const uint4*)(Ar0 + kt);
    uint4 a1 = *(const uint4*)(Ar1 + kt);
    uint4 b0 = *(const uint4*)(Br0 + kt);
    uint4 b1 = *(const uint4*)(Br1 + kt);
    __syncthreads();
    *(uint4*)&As[ls0] = a0;
    *(uint4*)&As[ls1] = a1;
    *(uint4*)&Bs[ls0] = b0;
    *(uint4*)&Bs[ls1] = b1;
    __syncthreads();
    half8 af[4], bf[4];
#pragma unroll
    for (int i = 0; i < 4; ++i)
      af[i] = *(const half8*)&As[(wm + 16 * i + mrow) * 40 + quad * 8];
#pragma unroll
    for (int j = 0; j < 4; ++j)
      bf[j] = *(const half8*)&Bs[(wn + 16 * j + mrow) * 40 + quad * 8];
#pragma unroll
    for (int i = 0; i < 4; ++i)
#pragma unroll
      for (int j = 0; j < 4; ++j)
        acc[i][j] = __builtin_amdgcn_mfma_f32_16x16x32_f16(af[i], bf[j], acc[i][j], 0, 0, 0);
  }
  int relu = flags & 1, h16 = flags & 2;
#pragma unroll
  for (int j = 0; j < 4; ++j) {
    int n = bn0 + wn + 16 * j + mrow;
    float bj = bias[n];
#pragma unroll
    for (int i = 0; i < 4; ++i) {
#pragma unroll
      for (int r = 0; r < 4; ++r) {
        long m = bm0 + wm + 16 * i + quad * 4 + r;
        float v = acc[i][j][r] + bj;
        if (relu) v = fmaxf(v, 0.f);
        if (h16) ((_Float16*)C)[m * N + n] = (_Float16)v;
        else     ((float*)C)[m * N + n] = v;
      }
    }
  }
}

// ---------------- Fused attention (fp16 in/out, fp32 math), one block per (row-block, head).
// Layout [rows, 512], feature = n*64 + h.
// mode_ca=0: Q,K,V,O chunk-local, block-row rl = idx>>3.
// mode_ca=1: O chunk-local at rl; g = rb0+rl = a*32+b; K/V from 1024-row buffer, batch a=g>>5;
//            Q at block (l0 ? g&31 : rl).
__global__ __launch_bounds__(256) void attn_h(
    const _Float16* __restrict__ Qp, const _Float16* __restrict__ Kp,
    const _Float16* __restrict__ Vp, _Float16* __restrict__ Op,
    int mode_ca, int l0, int rb0)
{
  __shared__ float Ks[128][68];
  __shared__ float Qs[32][68];
  __shared__ float Ss[32][132];
  __shared__ float rsum[32];
  int idx = blockIdx.x;
  int n = idx & 7;
  int rl = idx >> 3;
  long qbase, kbase, obase;
  obase = (long)rl * 128 * 512 + n * 64;
  if (!mode_ca) {
    qbase = obase; kbase = obase;
  } else {
    int g = rb0 + rl;
    int a = g >> 5;
    int qblk = l0 ? (g & 31) : rl;
    qbase = (long)qblk * 128 * 512 + n * 64;
    kbase = (long)a * 128 * 512 + n * 64;
  }
  int tid = threadIdx.x;
#pragma unroll
  for (int i = 0; i < 32; ++i) {
    int e = tid + i * 256;
    Ks[e >> 6][e & 63] = (float)Kp[kbase + (long)(e >> 6) * 512 + (e & 63)];
  }
  int r = tid >> 3, c0 = tid & 7;
  int hlane = tid & 63, rg = tid >> 6;
  for (int ch = 0; ch < 4; ++ch) {
    __syncthreads();
#pragma unroll
    for (int i = 0; i < 8; ++i) {
      int e = tid + i * 256;
      Qs[e >> 6][e & 63] = (float)Qp[qbase + (long)(ch * 32 + (e >> 6)) * 512 + (e & 63)];
    }
    __syncthreads();
    float acc[16];
#pragma unroll
    for (int j = 0; j < 16; ++j) acc[j] = 0.f;
    for (int h = 0; h < 64; h += 4) {
      float4 qv = *(const float4*)&Qs[r][h];
#pragma unroll
      for (int j = 0; j < 16; ++j) {
        float4 kv = *(const float4*)&Ks[c0 + j * 8][h];
        acc[j] += qv.x * kv.x + qv.y * kv.y + qv.z * kv.z + qv.w * kv.w;
      }
    }
    float mx = -1e30f;
#pragma unroll
    for (int j = 0; j < 16; ++j) { acc[j] *= 0.125f; mx = fmaxf(mx, acc[j]); }
#pragma unroll
    for (int off = 1; off < 8; off <<= 1) mx = fmaxf(mx, __shfl_xor(mx, off));
    float sum = 0.f;
#pragma unroll
    for (int j = 0; j < 16; ++j) { acc[j] = __expf(acc[j] - mx); sum += acc[j]; }
#pragma unroll
    for (int off = 1; off < 8; off <<= 1) sum += __shfl_xor(sum, off);
#pragma unroll
    for (int j = 0; j < 16; ++j) Ss[r][c0 + 8 * j] = acc[j];
    if (c0 == 0) rsum[r] = sum;
    __syncthreads();
    float ov[8];
#pragma unroll
    for (int i = 0; i < 8; ++i) ov[i] = 0.f;
    for (int k = 0; k < 128; ++k) {
      float v = (float)Vp[kbase + (long)k * 512 + hlane];
#pragma unroll
      for (int i = 0; i < 8; ++i) ov[i] += Ss[rg + 4 * i][k] * v;
    }
#pragma unroll
    for (int i = 0; i < 8; ++i) {
      int rr = rg + 4 * i;
      Op[obase + (long)(ch * 32 + rr) * 512 + hlane] = (_Float16)(ov[i] / rsum[rr]);
    }
  }
}

// ---------------- Residual + LayerNorm (rows of 512). One wave per row.
// out row = row0+rl (fp32), optional fp16 shadow copy xh; xin row = (row0+rl)&bmask.
__global__ __launch_bounds__(256) void ln_f32(
    const float* __restrict__ xin, const float* __restrict__ add,
    float* __restrict__ out, _Float16* __restrict__ xh,
    const float* __restrict__ g, const float* __restrict__ bt,
    long row0, int bmask)
{
  int rl = blockIdx.x * 4 + (threadIdx.x >> 6);
  long row = row0 + rl;
  int lane = threadIdx.x & 63;
  long xr = (row & (long)bmask) * 512 + lane * 8;
  float4 v0 = *(const float4*)&xin[xr];
  float4 v1 = *(const float4*)&xin[xr + 4];
  if (add) {
    long ar = (long)rl * 512 + lane * 8;
    float4 a0 = *(const float4*)&add[ar];
    float4 a1 = *(const float4*)&add[ar + 4];
    v0.x += a0.x; v0.y += a0.y; v0.z += a0.z; v0.w += a0.w;
    v1.x += a1.x; v1.y += a1.y; v1.z += a1.z; v1.w += a1.w;
  }
  float s = v0.x + v0.y + v0.z + v0.w + v1.x + v1.y + v1.z + v1.w;
  float sq = v0.x * v0.x + v0.y * v0.y + v0.z * v0.z + v0.w * v0.w
           + v1.x * v1.x + v1.y * v1.y + v1.z * v1.z + v1.w * v1.w;
#pragma unroll
  for (int off = 1; off < 64; off <<= 1) {
    s += __shfl_xor(s, off);
    sq += __shfl_xor(sq, off);
  }
  float mean = s * (1.f / 512.f);
  float var = sq * (1.f / 512.f) - mean * mean;
  float rst = rsqrtf(var + 1e-6f);
  int c = lane * 8;
  float4 g0 = *(const float4*)&g[c], g1 = *(const float4*)&g[c + 4];
  float4 b0 = *(const float4*)&bt[c], b1 = *(const float4*)&bt[c + 4];
  float4 o0, o1;
  o0.x = (v0.x - mean) * rst * g0.x + b0.x;
  o0.y = (v0.y - mean) * rst * g0.y + b0.y;
  o0.z = (v0.z - mean) * rst * g0.z + b0.z;
  o0.w = (v0.w - mean) * rst * g0.w + b0.w;
  o1.x = (v1.x - mean) * rst * g1.x + b1.x;
  o1.y = (v1.y - mean) * rst * g1.y + b1.y;
  o1.z = (v1.z - mean) * rst * g1.z + b1.z;
  o1.w = (v1.w - mean) * rst * g1.w + b1.w;
  long orow = row * 512 + c;
  *(float4*)&out[orow] = o0;
  *(float4*)&out[orow + 4] = o1;
  if (xh) {
    half8 hv;
    hv[0] = (_Float16)o0.x; hv[1] = (_Float16)o0.y;
    hv[2] = (_Float16)o0.z; hv[3] = (_Float16)o0.w;
    hv[4] = (_Float16)o1.x; hv[5] = (_Float16)o1.y;
    hv[6] = (_Float16)o1.z; hv[7] = (_Float16)o1.w;
    *(half8*)&xh[orow] = hv;
  }
}

// ---------------- transpose-convert: in fp32 [Rr][Cc] -> out fp16 [Cc][Rr]
__global__ __launch_bounds__(256) void tconv(const float* __restrict__ in,
                                             _Float16* __restrict__ out, int Rr, int Cc)
{
  __shared__ float T[64][65];
  int tx = threadIdx.x & 63, tg = threadIdx.x >> 6;
  int r0 = blockIdx.y * 64, c0 = blockIdx.x * 64;
#pragma unroll
  for (int i = 0; i < 16; ++i)
    T[tg + 4 * i][tx] = in[(long)(r0 + tg + 4 * i) * Cc + c0 + tx];
  __syncthreads();
#pragma unroll
  for (int i = 0; i < 16; ++i)
    out[(long)(c0 + tg + 4 * i) * Rr + r0 + tx] = (_Float16)T[tx][tg + 4 * i];
}

// ---------------- wo layer slice (8,512,64) fp32 -> [d=512][n*64+h=512] fp16
__global__ void woconv(const float* __restrict__ wo, _Float16* __restrict__ out)
{
  int o = blockIdx.x * 256 + threadIdx.x;  // 262144
  int d = o >> 9;
  int nh = o & 511;
  int n = nh >> 6, h = nh & 63;
  out[o] = (_Float16)wo[((long)(n << 9) + d) * 64 + h];
}

__global__ void f2h(const float* __restrict__ in, _Float16* __restrict__ out, long n)
{
  long i = blockIdx.x * 256L + threadIdx.x;
  if (i < n) out[i] = (_Float16)in[i];
}

// ---------------- mean over tokens 1..127 of [ab, 128, 512] -> [ab, 512]
__global__ void pool_mean(const float* __restrict__ X, float* __restrict__ P)
{
  int ab = blockIdx.x;
  for (int dd = threadIdx.x; dd < 512; dd += 256) {
    const float* base = X + (long)ab * 128 * 512 + dd;
    float sacc = 0.f;
    for (int t = 1; t < 128; ++t) sacc += base[t * 512];
    P[ab * 512 + dd] = sacc * (1.f / 127.f);
  }
}

__global__ void featq_kernel(const float* __restrict__ QP, const float* __restrict__ W,
                             const float* __restrict__ bias, float* __restrict__ QN)
{
  int a = blockIdx.x;
  int f = threadIdx.x;
  float acc = bias[f];
  const float* xr = QP + a * 512;
  for (int d = 0; d < 512; ++d) acc += xr[d] * W[d * 256 + f];
  __shared__ float red[256];
  red[f] = acc * acc;
  __syncthreads();
  for (int s = 128; s > 0; s >>= 1) {
    if (f < s) red[f] += red[f + s];
    __syncthreads();
  }
  float rn = rsqrtf(fmaxf(red[0], 1e-12f));
  QN[a * 256 + f] = acc * rn;
}

__global__ void featc_kernel(const float* __restrict__ CP, const float* __restrict__ W,
                             const float* __restrict__ bias, const float* __restrict__ QN,
                             float* __restrict__ out)
{
  int ab = blockIdx.x;
  int f = threadIdx.x;
  float acc = bias[f];
  const float* xr = CP + ab * 512;
  for (int d = 0; d < 512; ++d) acc += xr[d] * W[d * 256 + f];
  __shared__ float red[256];
  red[f] = acc * acc;
  __syncthreads();
  for (int s = 128; s > 0; s >>= 1) {
    if (f < s) red[f] += red[f + s];
    __syncthreads();
  }
  float rn = rsqrtf(fmaxf(red[0], 1e-12f));
  float v = acc * rn * QN[(ab >> 5) * 256 + f];
  __syncthreads();
  red[f] = v;
  __syncthreads();
  for (int s = 128; s > 0; s >>= 1) {
    if (f < s) red[f] += red[f + s];
    __syncthreads();
  }
  if (f == 0) out[ab] = red[0];
}

extern "C" void kernel_launch(void* const* d_in, const int* in_sizes, int n_in,
                              void* d_out, int out_size, void* d_ws, size_t ws_size,
                              hipStream_t stream)
{
  (void)in_sizes; (void)n_in; (void)out_size;
  const float* c_in  = (const float*)d_in[0];
  const float* q_in  = (const float*)d_in[1];
  const float* sa_wq = (const float*)d_in[2];
  const float* sa_bq = (const float*)d_in[3];
  const float* sa_wk = (const float*)d_in[4];
  const float* sa_bk = (const float*)d_in[5];
  const float* sa_wv = (const float*)d_in[6];
  const float* sa_bv = (const float*)d_in[7];
  const float* sa_wo = (const float*)d_in[8];
  const float* sa_bo = (const float*)d_in[9];
  const float* ca_wq = (const float*)d_in[10];
  const float* ca_bq = (const float*)d_in[11];
  const float* ca_wk = (const float*)d_in[12];
  const float* ca_bk = (const float*)d_in[13];
  const float* ca_wv = (const float*)d_in[14];
  const float* ca_bv = (const float*)d_in[15];
  const float* ca_wo = (const float*)d_in[16];
  const float* ca_bo = (const float*)d_in[17];
  const float* ln1_g = (const float*)d_in[18];
  const float* ln1_b = (const float*)d_in[19];
  const float* ln2_g = (const float*)d_in[20];
  const float* ln2_b = (const float*)d_in[21];
  const float* ln3_g = (const float*)d_in[22];
  const float* ln3_b = (const float*)d_in[23];
  const float* ffn_w1 = (const float*)d_in[24];
  const float* ffn_b1 = (const float*)d_in[25];
  const float* ffn_w2 = (const float*)d_in[26];
  const float* ffn_b2 = (const float*)d_in[27];
  const float* lnf_g  = (const float*)d_in[28];
  const float* lnf_b  = (const float*)d_in[29];
  const float* feat_wq = (const float*)d_in[30];
  const float* feat_bq = (const float*)d_in[31];
  const float* feat_wc = (const float*)d_in[32];
  const float* feat_bc = (const float*)d_in[33];

  // ---- workspace layout (bytes), ws_size-adaptive chunk R
  char* p = (char*)d_ws;
  float*    X   = (float*)p;     p += 67108864;   // 32768 x 512 fp32
  _Float16* Xh  = (_Float16*)p;  p += 33554432;   // 32768 x 512 fp16
  float*    Xs  = (float*)p;     p += 8388608;    //  4096 x 512 fp32
  _Float16* Xsh = (_Float16*)p;  p += 4194304;    //  4096 x 512 fp16
  _Float16* Wh  = (_Float16*)p;  p += 16777216;   // fp16 transposed weights arena
  _Float16* qh  = (_Float16*)p;  p += 1048576;    //  1024 x 512 fp16
  _Float16* K0  = (_Float16*)p;  p += 1048576;
  _Float16* V0  = (_Float16*)p;  p += 1048576;
  float*    CP  = (float*)p;     p += 524288;
  float*    QP  = (float*)p;     p += 16384;
  float*    QN  = (float*)p;     p += 8192;
  const size_t fixed_b = (size_t)(p - (char*)d_ws);
  long R = 4096;
  if (ws_size >= fixed_b + 32768L * 6144) R = 32768;
  else if (ws_size >= fixed_b + 16384L * 6144) R = 16384;
  else if (ws_size >= fixed_b + 8192L * 6144) R = 8192;
  _Float16* Qc = (_Float16*)p;   p += R * 1024;
  _Float16* Kc = (_Float16*)p;   p += R * 1024;
  _Float16* Vc = (_Float16*)p;   p += R * 1024;
  _Float16* Oc = (_Float16*)p;   p += R * 1024;
  float*    Ac = (float*)p;
  _Float16* Hb = Kc;             // FFN hidden (R/2 x 2048) aliases Kc+Vc
  const long Rh = R / 2;

  // ---- prep: fp16 conversions + weight transposes
  f2h<<<8192, 256, 0, stream>>>(c_in, Xsh, 2097152);
  f2h<<<2048, 256, 0, stream>>>(q_in, qh, 524288);
  for (int l = 0; l < 2; ++l) {
    _Float16* Wl = Wh + (long)l * 4194304;
    long woff = (long)l * 262144;
    tconv<<<dim3(8, 8), 256, 0, stream>>>(sa_wq + woff, Wl + 0, 512, 512);
    tconv<<<dim3(8, 8), 256, 0, stream>>>(sa_wk + woff, Wl + 262144, 512, 512);
    tconv<<<dim3(8, 8), 256, 0, stream>>>(sa_wv + woff, Wl + 524288, 512, 512);
    woconv<<<1024, 256, 0, stream>>>(sa_wo + woff, Wl + 786432);
    tconv<<<dim3(8, 8), 256, 0, stream>>>(ca_wq + woff, Wl + 1048576, 512, 512);
    tconv<<<dim3(8, 8), 256, 0, stream>>>(ca_wk + woff, Wl + 1310720, 512, 512);
    tconv<<<dim3(8, 8), 256, 0, stream>>>(ca_wv + woff, Wl + 1572864, 512, 512);
    woconv<<<1024, 256, 0, stream>>>(ca_wo + woff, Wl + 1835008);
    tconv<<<dim3(32, 8), 256, 0, stream>>>(ffn_w1 + (long)l * 1048576, Wl + 2097152, 512, 2048);
    tconv<<<dim3(8, 32), 256, 0, stream>>>(ffn_w2 + (long)l * 1048576, Wl + 3145728, 2048, 512);
  }

  // =================== layer 0 (x rows = 4096) ===================
  {
    _Float16* Wl = Wh;
    dim3 g4k(4, 32);
    gemm_h<<<g4k, 256, 0, stream>>>(Xsh, Wl + 0,      sa_bq, Qc, 4096, 512, 512, 2);
    gemm_h<<<g4k, 256, 0, stream>>>(Xsh, Wl + 262144, sa_bk, Kc, 4096, 512, 512, 2);
    gemm_h<<<g4k, 256, 0, stream>>>(Xsh, Wl + 524288, sa_bv, Vc, 4096, 512, 512, 2);
    attn_h<<<256, 256, 0, stream>>>(Qc, Kc, Vc, Oc, 0, 0, 0);
    gemm_h<<<g4k, 256, 0, stream>>>(Oc, Wl + 786432, sa_bo, Ac, 4096, 512, 512, 0);
    ln_f32<<<1024, 256, 0, stream>>>(c_in, Ac, Xs, Xsh, ln1_g, ln1_b, 0, 0x7FFFFFFF);
    gemm_h<<<g4k, 256, 0, stream>>>(Xsh, Wl + 1048576, ca_bq, Qc, 4096, 512, 512, 2);
    gemm_h<<<dim3(4, 8), 256, 0, stream>>>(qh, Wl + 1310720, ca_bk, K0, 1024, 512, 512, 2);
    gemm_h<<<dim3(4, 8), 256, 0, stream>>>(qh, Wl + 1572864, ca_bv, V0, 1024, 512, 512, 2);
    for (long c = 0; c < 32768; c += R) {
      attn_h<<<(R / 128) * 8, 256, 0, stream>>>(Qc, K0, V0, Oc, 1, 1, (int)(c / 128));
      gemm_h<<<dim3(4, R / 128), 256, 0, stream>>>(Oc, Wl + 1835008, ca_bo, Ac, (int)R, 512, 512, 0);
      ln_f32<<<R / 4, 256, 0, stream>>>(Xs, Ac, X, Xh, ln2_g, ln2_b, c, 4095);
      for (long s = 0; s < R; s += Rh) {
        gemm_h<<<dim3(16, Rh / 128), 256, 0, stream>>>(Xh + (c + s) * 512, Wl + 2097152,
                                                       ffn_b1, Hb, (int)Rh, 2048, 512, 3);
        gemm_h<<<dim3(4, Rh / 128), 256, 0, stream>>>(Hb, Wl + 3145728, ffn_b2,
                                                      Ac + s * 512, (int)Rh, 512, 2048, 0);
      }
      ln_f32<<<R / 4, 256, 0, stream>>>(X, Ac, X, Xh, ln3_g, ln3_b, c, 0x7FFFFFFF);
    }
  }
  // =================== layer 1 (x rows = 32768, chunked by R) ===================
  {
    _Float16* Wl = Wh + 4194304;
    gemm_h<<<dim3(4, 8), 256, 0, stream>>>(qh, Wl + 1310720, ca_bk + 512, K0, 1024, 512, 512, 2);
    gemm_h<<<dim3(4, 8), 256, 0, stream>>>(qh, Wl + 1572864, ca_bv + 512, V0, 1024, 512, 512, 2);
    dim3 gR(4, R / 128);
    for (long c = 0; c < 32768; c += R) {
      _Float16* Xhc = Xh + c * 512;
      gemm_h<<<gR, 256, 0, stream>>>(Xhc, Wl + 0,      sa_bq + 512, Qc, (int)R, 512, 512, 2);
      gemm_h<<<gR, 256, 0, stream>>>(Xhc, Wl + 262144, sa_bk + 512, Kc, (int)R, 512, 512, 2);
      gemm_h<<<gR, 256, 0, stream>>>(Xhc, Wl + 524288, sa_bv + 512, Vc, (int)R, 512, 512, 2);
      attn_h<<<(R / 128) * 8, 256, 0, stream>>>(Qc, Kc, Vc, Oc, 0, 0, 0);
      gemm_h<<<gR, 256, 0, stream>>>(Oc, Wl + 786432, sa_bo + 512, Ac, (int)R, 512, 512, 0);
      ln_f32<<<R / 4, 256, 0, stream>>>(X, Ac, X, Xh, ln1_g + 512, ln1_b + 512, c, 0x7FFFFFFF);
      gemm_h<<<gR, 256, 0, stream>>>(Xhc, Wl + 1048576, ca_bq + 512, Qc, (int)R, 512, 512, 2);
      attn_h<<<(R / 128) * 8, 256, 0, stream>>>(Qc, K0, V0, Oc, 1, 0, (int)(c / 128));
      gemm_h<<<gR, 256, 0, stream>>>(Oc, Wl + 1835008, ca_bo + 512, Ac, (int)R, 512, 512, 0);
      ln_f32<<<R / 4, 256, 0, stream>>>(X, Ac, X, Xh, ln2_g + 512, ln2_b + 512, c, 0x7FFFFFFF);
      for (long s = 0; s < R; s += Rh) {
        gemm_h<<<dim3(16, Rh / 128), 256, 0, stream>>>(Xh + (c + s) * 512, Wl + 2097152,
                                                       ffn_b1 + 2048, Hb, (int)Rh, 2048, 512, 3);
        gemm_h<<<dim3(4, Rh / 128), 256, 0, stream>>>(Hb, Wl + 3145728, ffn_b2 + 512,
                                                      Ac + s * 512, (int)Rh, 512, 2048, 0);
      }
      ln_f32<<<R / 4, 256, 0, stream>>>(X, Ac, X, Xh, ln3_g + 512, ln3_b + 512, c, 0x7FFFFFFF);
    }
  }
  // =================== final LN + pooling + features + cosine ===================
  ln_f32<<<8192, 256, 0, stream>>>(X, nullptr, X, nullptr, lnf_g, lnf_b, 0, 0x7FFFFFFF);
  pool_mean<<<256, 256, 0, stream>>>(X, CP);
  pool_mean<<<8, 256, 0, stream>>>(q_in, QP);
  featq_kernel<<<8, 256, 0, stream>>>(QP, feat_wq, feat_bq, QN);
  featc_kernel<<<256, 256, 0, stream>>>(CP, feat_wc, feat_bc, QN, (float*)d_out);
}

// Round 4
// 2396.893 us; speedup vs baseline: 2.8812x; 1.0041x over previous
//
#include <hip/hip_runtime.h>

using half8  = __attribute__((ext_vector_type(8))) _Float16;
using floatx4 = __attribute__((ext_vector_type(4))) float;

__device__ __forceinline__ void gl_lds16(const _Float16* g, _Float16* l)
{
  __builtin_amdgcn_global_load_lds(
      (const __attribute__((address_space(1))) void*)g,
      (__attribute__((address_space(3))) void*)l, 16, 0, 0);
}

// ---------------- MFMA fp16 GEMM: C[M,N] = A[M,K] @ Bt[N,K]^T + bias[N]
// A fp16 [M][K], Bt fp16 [N][K] (pre-transposed), C fp32 or fp16 per flags.
// flags: bit0 = relu, bit1 = fp16 output. M%128==0, N%128==0, K%32==0.
// Block 256 threads = 4 waves; 128x128 tile; wave = 64x64 via 4x4 MFMA 16x16x32.
// Staging: global_load_lds width=16 into UNPADDED [128][32]-half tiles
// (lds dest is wave-uniform base + lane*16 -> layout must be linear).
__global__ __launch_bounds__(256) void gemm_h(
    const _Float16* __restrict__ A, const _Float16* __restrict__ Bt,
    const float* __restrict__ bias, void* __restrict__ C,
    int M, int N, int K, int flags)
{
  __shared__ _Float16 As[128 * 32];
  __shared__ _Float16 Bs[128 * 32];
  int tid = threadIdx.x;
  int lane = tid & 63, wave = tid >> 6;
  long bm0 = (long)blockIdx.y * 128;
  int bn0 = blockIdx.x * 128;
  int wm = (wave & 1) * 64, wn = (wave >> 1) * 64;
  // staging addresses: wave w covers tile rows [16w,16w+16) and [64+16w, 64+16w+16)
  int srow = wave * 16 + (lane >> 2);
  int scol = (lane & 3) * 8;
  const _Float16* aA0 = A + (bm0 + srow) * (long)K + scol;
  const _Float16* aA1 = aA0 + 64 * (long)K;
  const _Float16* aB0 = Bt + (bn0 + srow) * (long)K + scol;
  const _Float16* aB1 = aB0 + 64 * (long)K;
  _Float16* lA0 = As + wave * 512;          // wave-uniform LDS bases
  _Float16* lA1 = As + 2048 + wave * 512;
  _Float16* lB0 = Bs + wave * 512;
  _Float16* lB1 = Bs + 2048 + wave * 512;
  int mrow = lane & 15, quad = lane >> 4;
  floatx4 acc[4][4];
#pragma unroll
  for (int i = 0; i < 4; ++i)
#pragma unroll
    for (int j = 0; j < 4; ++j) acc[i][j] = (floatx4){0.f, 0.f, 0.f, 0.f};

  for (int kt = 0; kt < K; kt += 32) {
    __syncthreads();            // all waves done reading previous tile
    gl_lds16(aA0 + kt, lA0);
    gl_lds16(aA1 + kt, lA1);
    gl_lds16(aB0 + kt, lB0);
    gl_lds16(aB1 + kt, lB1);
    __syncthreads();            // vmcnt(0) drain: staged tile visible
    half8 af[4], bf[4];
#pragma unroll
    for (int i = 0; i < 4; ++i)
      af[i] = *(const half8*)&As[(wm + 16 * i + mrow) * 32 + quad * 8];
#pragma unroll
    for (int j = 0; j < 4; ++j)
      bf[j] = *(const half8*)&Bs[(wn + 16 * j + mrow) * 32 + quad * 8];
#pragma unroll
    for (int i = 0; i < 4; ++i)
#pragma unroll
      for (int j = 0; j < 4; ++j)
        acc[i][j] = __builtin_amdgcn_mfma_f32_16x16x32_f16(af[i], bf[j], acc[i][j], 0, 0, 0);
  }
  int relu = flags & 1, h16 = flags & 2;
#pragma unroll
  for (int j = 0; j < 4; ++j) {
    int n = bn0 + wn + 16 * j + mrow;
    float bj = bias[n];
#pragma unroll
    for (int i = 0; i < 4; ++i) {
#pragma unroll
      for (int r = 0; r < 4; ++r) {
        long m = bm0 + wm + 16 * i + quad * 4 + r;
        float v = acc[i][j][r] + bj;
        if (relu) v = fmaxf(v, 0.f);
        if (h16) ((_Float16*)C)[m * N + n] = (_Float16)v;
        else     ((float*)C)[m * N + n] = v;
      }
    }
  }
}

// ---------------- Fused attention (fp16 in/out, fp32 math), one block per (row-block, head).
// Layout [rows, 512], feature = n*64 + h.
// mode_ca=0: Q,K,V,O chunk-local, block-row rl = idx>>3.
// mode_ca=1: O chunk-local at rl; g = rb0+rl = a*32+b; K/V from 1024-row buffer, batch a=g>>5;
//            Q at block (l0 ? g&31 : rl).
__global__ __launch_bounds__(256) void attn_h(
    const _Float16* __restrict__ Qp, const _Float16* __restrict__ Kp,
    const _Float16* __restrict__ Vp, _Float16* __restrict__ Op,
    int mode_ca, int l0, int rb0)
{
  __shared__ float Ks[128][68];
  __shared__ float Qs[32][68];
  __shared__ float Ss[32][132];
  __shared__ float rsum[32];
  int idx = blockIdx.x;
  int n = idx & 7;
  int rl = idx >> 3;
  long qbase, kbase, obase;
  obase = (long)rl * 128 * 512 + n * 64;
  if (!mode_ca) {
    qbase = obase; kbase = obase;
  } else {
    int g = rb0 + rl;
    int a = g >> 5;
    int qblk = l0 ? (g & 31) : rl;
    qbase = (long)qblk * 128 * 512 + n * 64;
    kbase = (long)a * 128 * 512 + n * 64;
  }
  int tid = threadIdx.x;
#pragma unroll
  for (int i = 0; i < 32; ++i) {
    int e = tid + i * 256;
    Ks[e >> 6][e & 63] = (float)Kp[kbase + (long)(e >> 6) * 512 + (e & 63)];
  }
  int r = tid >> 3, c0 = tid & 7;
  int hlane = tid & 63, rg = tid >> 6;
  for (int ch = 0; ch < 4; ++ch) {
    __syncthreads();
#pragma unroll
    for (int i = 0; i < 8; ++i) {
      int e = tid + i * 256;
      Qs[e >> 6][e & 63] = (float)Qp[qbase + (long)(ch * 32 + (e >> 6)) * 512 + (e & 63)];
    }
    __syncthreads();
    float acc[16];
#pragma unroll
    for (int j = 0; j < 16; ++j) acc[j] = 0.f;
    for (int h = 0; h < 64; h += 4) {
      float4 qv = *(const float4*)&Qs[r][h];
#pragma unroll
      for (int j = 0; j < 16; ++j) {
        float4 kv = *(const float4*)&Ks[c0 + j * 8][h];
        acc[j] += qv.x * kv.x + qv.y * kv.y + qv.z * kv.z + qv.w * kv.w;
      }
    }
    float mx = -1e30f;
#pragma unroll
    for (int j = 0; j < 16; ++j) { acc[j] *= 0.125f; mx = fmaxf(mx, acc[j]); }
#pragma unroll
    for (int off = 1; off < 8; off <<= 1) mx = fmaxf(mx, __shfl_xor(mx, off));
    float sum = 0.f;
#pragma unroll
    for (int j = 0; j < 16; ++j) { acc[j] = __expf(acc[j] - mx); sum += acc[j]; }
#pragma unroll
    for (int off = 1; off < 8; off <<= 1) sum += __shfl_xor(sum, off);
#pragma unroll
    for (int j = 0; j < 16; ++j) Ss[r][c0 + 8 * j] = acc[j];
    if (c0 == 0) rsum[r] = sum;
    __syncthreads();
    float ov[8];
#pragma unroll
    for (int i = 0; i < 8; ++i) ov[i] = 0.f;
    for (int k = 0; k < 128; ++k) {
      float v = (float)Vp[kbase + (long)k * 512 + hlane];
#pragma unroll
      for (int i = 0; i < 8; ++i) ov[i] += Ss[rg + 4 * i][k] * v;
    }
#pragma unroll
    for (int i = 0; i < 8; ++i) {
      int rr = rg + 4 * i;
      Op[obase + (long)(ch * 32 + rr) * 512 + hlane] = (_Float16)(ov[i] / rsum[rr]);
    }
  }
}

// ---------------- Residual + LayerNorm (rows of 512). One wave per row.
// out row = row0+rl (fp32), optional fp16 shadow copy xh; xin row = (row0+rl)&bmask.
__global__ __launch_bounds__(256) void ln_f32(
    const float* __restrict__ xin, const float* __restrict__ add,
    float* __restrict__ out, _Float16* __restrict__ xh,
    const float* __restrict__ g, const float* __restrict__ bt,
    long row0, int bmask)
{
  int rl = blockIdx.x * 4 + (threadIdx.x >> 6);
  long row = row0 + rl;
  int lane = threadIdx.x & 63;
  long xr = (row & (long)bmask) * 512 + lane * 8;
  float4 v0 = *(const float4*)&xin[xr];
  float4 v1 = *(const float4*)&xin[xr + 4];
  if (add) {
    long ar = (long)rl * 512 + lane * 8;
    float4 a0 = *(const float4*)&add[ar];
    float4 a1 = *(const float4*)&add[ar + 4];
    v0.x += a0.x; v0.y += a0.y; v0.z += a0.z; v0.w += a0.w;
    v1.x += a1.x; v1.y += a1.y; v1.z += a1.z; v1.w += a1.w;
  }
  float s = v0.x + v0.y + v0.z + v0.w + v1.x + v1.y + v1.z + v1.w;
  float sq = v0.x * v0.x + v0.y * v0.y + v0.z * v0.z + v0.w * v0.w
           + v1.x * v1.x + v1.y * v1.y + v1.z * v1.z + v1.w * v1.w;
#pragma unroll
  for (int off = 1; off < 64; off <<= 1) {
    s += __shfl_xor(s, off);
    sq += __shfl_xor(sq, off);
  }
  float mean = s * (1.f / 512.f);
  float var = sq * (1.f / 512.f) - mean * mean;
  float rst = rsqrtf(var + 1e-6f);
  int c = lane * 8;
  float4 g0 = *(const float4*)&g[c], g1 = *(const float4*)&g[c + 4];
  float4 b0 = *(const float4*)&bt[c], b1 = *(const float4*)&bt[c + 4];
  float4 o0, o1;
  o0.x = (v0.x - mean) * rst * g0.x + b0.x;
  o0.y = (v0.y - mean) * rst * g0.y + b0.y;
  o0.z = (v0.z - mean) * rst * g0.z + b0.z;
  o0.w = (v0.w - mean) * rst * g0.w + b0.w;
  o1.x = (v1.x - mean) * rst * g1.x + b1.x;
  o1.y = (v1.y - mean) * rst * g1.y + b1.y;
  o1.z = (v1.z - mean) * rst * g1.z + b1.z;
  o1.w = (v1.w - mean) * rst * g1.w + b1.w;
  long orow = row * 512 + c;
  *(float4*)&out[orow] = o0;
  *(float4*)&out[orow + 4] = o1;
  if (xh) {
    half8 hv;
    hv[0] = (_Float16)o0.x; hv[1] = (_Float16)o0.y;
    hv[2] = (_Float16)o0.z; hv[3] = (_Float16)o0.w;
    hv[4] = (_Float16)o1.x; hv[5] = (_Float16)o1.y;
    hv[6] = (_Float16)o1.z; hv[7] = (_Float16)o1.w;
    *(half8*)&xh[orow] = hv;
  }
}

// ---------------- transpose-convert: in fp32 [Rr][Cc] -> out fp16 [Cc][Rr]
__global__ __launch_bounds__(256) void tconv(const float* __restrict__ in,
                                             _Float16* __restrict__ out, int Rr, int Cc)
{
  __shared__ float T[64][65];
  int tx = threadIdx.x & 63, tg = threadIdx.x >> 6;
  int r0 = blockIdx.y * 64, c0 = blockIdx.x * 64;
#pragma unroll
  for (int i = 0; i < 16; ++i)
    T[tg + 4 * i][tx] = in[(long)(r0 + tg + 4 * i) * Cc + c0 + tx];
  __syncthreads();
#pragma unroll
  for (int i = 0; i < 16; ++i)
    out[(long)(c0 + tg + 4 * i) * Rr + r0 + tx] = (_Float16)T[tx][tg + 4 * i];
}

// ---------------- wo layer slice (8,512,64) fp32 -> [d=512][n*64+h=512] fp16
__global__ void woconv(const float* __restrict__ wo, _Float16* __restrict__ out)
{
  int o = blockIdx.x * 256 + threadIdx.x;  // 262144
  int d = o >> 9;
  int nh = o & 511;
  int n = nh >> 6, h = nh & 63;
  out[o] = (_Float16)wo[((long)(n << 9) + d) * 64 + h];
}

__global__ void f2h(const float* __restrict__ in, _Float16* __restrict__ out, long n)
{
  long i = blockIdx.x * 256L + threadIdx.x;
  if (i < n) out[i] = (_Float16)in[i];
}

// ---------------- mean over tokens 1..127 of [ab, 128, 512] -> [ab, 512]
__global__ void pool_mean(const float* __restrict__ X, float* __restrict__ P)
{
  int ab = blockIdx.x;
  for (int dd = threadIdx.x; dd < 512; dd += 256) {
    const float* base = X + (long)ab * 128 * 512 + dd;
    float sacc = 0.f;
    for (int t = 1; t < 128; ++t) sacc += base[t * 512];
    P[ab * 512 + dd] = sacc * (1.f / 127.f);
  }
}

__global__ void featq_kernel(const float* __restrict__ QP, const float* __restrict__ W,
                             const float* __restrict__ bias, float* __restrict__ QN)
{
  int a = blockIdx.x;
  int f = threadIdx.x;
  float acc = bias[f];
  const float* xr = QP + a * 512;
  for (int d = 0; d < 512; ++d) acc += xr[d] * W[d * 256 + f];
  __shared__ float red[256];
  red[f] = acc * acc;
  __syncthreads();
  for (int s = 128; s > 0; s >>= 1) {
    if (f < s) red[f] += red[f + s];
    __syncthreads();
  }
  float rn = rsqrtf(fmaxf(red[0], 1e-12f));
  QN[a * 256 + f] = acc * rn;
}

__global__ void featc_kernel(const float* __restrict__ CP, const float* __restrict__ W,
                             const float* __restrict__ bias, const float* __restrict__ QN,
                             float* __restrict__ out)
{
  int ab = blockIdx.x;
  int f = threadIdx.x;
  float acc = bias[f];
  const float* xr = CP + ab * 512;
  for (int d = 0; d < 512; ++d) acc += xr[d] * W[d * 256 + f];
  __shared__ float red[256];
  red[f] = acc * acc;
  __syncthreads();
  for (int s = 128; s > 0; s >>= 1) {
    if (f < s) red[f] += red[f + s];
    __syncthreads();
  }
  float rn = rsqrtf(fmaxf(red[0], 1e-12f));
  float v = acc * rn * QN[(ab >> 5) * 256 + f];
  __syncthreads();
  red[f] = v;
  __syncthreads();
  for (int s = 128; s > 0; s >>= 1) {
    if (f < s) red[f] += red[f + s];
    __syncthreads();
  }
  if (f == 0) out[ab] = red[0];
}

extern "C" void kernel_launch(void* const* d_in, const int* in_sizes, int n_in,
                              void* d_out, int out_size, void* d_ws, size_t ws_size,
                              hipStream_t stream)
{
  (void)in_sizes; (void)n_in; (void)out_size;
  const float* c_in  = (const float*)d_in[0];
  const float* q_in  = (const float*)d_in[1];
  const float* sa_wq = (const float*)d_in[2];
  const float* sa_bq = (const float*)d_in[3];
  const float* sa_wk = (const float*)d_in[4];
  const float* sa_bk = (const float*)d_in[5];
  const float* sa_wv = (const float*)d_in[6];
  const float* sa_bv = (const float*)d_in[7];
  const float* sa_wo = (const float*)d_in[8];
  const float* sa_bo = (const float*)d_in[9];
  const float* ca_wq = (const float*)d_in[10];
  const float* ca_bq = (const float*)d_in[11];
  const float* ca_wk = (const float*)d_in[12];
  const float* ca_bk = (const float*)d_in[13];
  const float* ca_wv = (const float*)d_in[14];
  const float* ca_bv = (const float*)d_in[15];
  const float* ca_wo = (const float*)d_in[16];
  const float* ca_bo = (const float*)d_in[17];
  const float* ln1_g = (const float*)d_in[18];
  const float* ln1_b = (const float*)d_in[19];
  const float* ln2_g = (const float*)d_in[20];
  const float* ln2_b = (const float*)d_in[21];
  const float* ln3_g = (const float*)d_in[22];
  const float* ln3_b = (const float*)d_in[23];
  const float* ffn_w1 = (const float*)d_in[24];
  const float* ffn_b1 = (const float*)d_in[25];
  const float* ffn_w2 = (const float*)d_in[26];
  const float* ffn_b2 = (const float*)d_in[27];
  const float* lnf_g  = (const float*)d_in[28];
  const float* lnf_b  = (const float*)d_in[29];
  const float* feat_wq = (const float*)d_in[30];
  const float* feat_bq = (const float*)d_in[31];
  const float* feat_wc = (const float*)d_in[32];
  const float* feat_bc = (const float*)d_in[33];

  // ---- workspace layout (bytes), ws_size-adaptive chunk R
  char* p = (char*)d_ws;
  float*    X   = (float*)p;     p += 67108864;   // 32768 x 512 fp32
  _Float16* Xh  = (_Float16*)p;  p += 33554432;   // 32768 x 512 fp16
  float*    Xs  = (float*)p;     p += 8388608;    //  4096 x 512 fp32
  _Float16* Xsh = (_Float16*)p;  p += 4194304;    //  4096 x 512 fp16
  _Float16* Wh  = (_Float16*)p;  p += 16777216;   // fp16 transposed weights arena
  _Float16* qh  = (_Float16*)p;  p += 1048576;    //  1024 x 512 fp16
  _Float16* K0  = (_Float16*)p;  p += 1048576;
  _Float16* V0  = (_Float16*)p;  p += 1048576;
  float*    CP  = (float*)p;     p += 524288;
  float*    QP  = (float*)p;     p += 16384;
  float*    QN  = (float*)p;     p += 8192;
  const size_t fixed_b = (size_t)(p - (char*)d_ws);
  long R = 4096;
  if (ws_size >= fixed_b + 32768L * 6144) R = 32768;
  else if (ws_size >= fixed_b + 16384L * 6144) R = 16384;
  else if (ws_size >= fixed_b + 8192L * 6144) R = 8192;
  _Float16* Qc = (_Float16*)p;   p += R * 1024;
  _Float16* Kc = (_Float16*)p;   p += R * 1024;
  _Float16* Vc = (_Float16*)p;   p += R * 1024;
  _Float16* Oc = (_Float16*)p;   p += R * 1024;
  float*    Ac = (float*)p;
  _Float16* Hb = Kc;             // FFN hidden (R/2 x 2048) aliases Kc+Vc
  const long Rh = R / 2;

  // ---- prep: fp16 conversions + weight transposes
  f2h<<<8192, 256, 0, stream>>>(c_in, Xsh, 2097152);
  f2h<<<2048, 256, 0, stream>>>(q_in, qh, 524288);
  for (int l = 0; l < 2; ++l) {
    _Float16* Wl = Wh + (long)l * 4194304;
    long woff = (long)l * 262144;
    tconv<<<dim3(8, 8), 256, 0, stream>>>(sa_wq + woff, Wl + 0, 512, 512);
    tconv<<<dim3(8, 8), 256, 0, stream>>>(sa_wk + woff, Wl + 262144, 512, 512);
    tconv<<<dim3(8, 8), 256, 0, stream>>>(sa_wv + woff, Wl + 524288, 512, 512);
    woconv<<<1024, 256, 0, stream>>>(sa_wo + woff, Wl + 786432);
    tconv<<<dim3(8, 8), 256, 0, stream>>>(ca_wq + woff, Wl + 1048576, 512, 512);
    tconv<<<dim3(8, 8), 256, 0, stream>>>(ca_wk + woff, Wl + 1310720, 512, 512);
    tconv<<<dim3(8, 8), 256, 0, stream>>>(ca_wv + woff, Wl + 1572864, 512, 512);
    woconv<<<1024, 256, 0, stream>>>(ca_wo + woff, Wl + 1835008);
    tconv<<<dim3(32, 8), 256, 0, stream>>>(ffn_w1 + (long)l * 1048576, Wl + 2097152, 512, 2048);
    tconv<<<dim3(8, 32), 256, 0, stream>>>(ffn_w2 + (long)l * 1048576, Wl + 3145728, 2048, 512);
  }

  // =================== layer 0 (x rows = 4096) ===================
  {
    _Float16* Wl = Wh;
    dim3 g4k(4, 32);
    gemm_h<<<g4k, 256, 0, stream>>>(Xsh, Wl + 0,      sa_bq, Qc, 4096, 512, 512, 2);
    gemm_h<<<g4k, 256, 0, stream>>>(Xsh, Wl + 262144, sa_bk, Kc, 4096, 512, 512, 2);
    gemm_h<<<g4k, 256, 0, stream>>>(Xsh, Wl + 524288, sa_bv, Vc, 4096, 512, 512, 2);
    attn_h<<<256, 256, 0, stream>>>(Qc, Kc, Vc, Oc, 0, 0, 0);
    gemm_h<<<g4k, 256, 0, stream>>>(Oc, Wl + 786432, sa_bo, Ac, 4096, 512, 512, 0);
    ln_f32<<<1024, 256, 0, stream>>>(c_in, Ac, Xs, Xsh, ln1_g, ln1_b, 0, 0x7FFFFFFF);
    gemm_h<<<g4k, 256, 0, stream>>>(Xsh, Wl + 1048576, ca_bq, Qc, 4096, 512, 512, 2);
    gemm_h<<<dim3(4, 8), 256, 0, stream>>>(qh, Wl + 1310720, ca_bk, K0, 1024, 512, 512, 2);
    gemm_h<<<dim3(4, 8), 256, 0, stream>>>(qh, Wl + 1572864, ca_bv, V0, 1024, 512, 512, 2);
    for (long c = 0; c < 32768; c += R) {
      attn_h<<<(R / 128) * 8, 256, 0, stream>>>(Qc, K0, V0, Oc, 1, 1, (int)(c / 128));
      gemm_h<<<dim3(4, R / 128), 256, 0, stream>>>(Oc, Wl + 1835008, ca_bo, Ac, (int)R, 512, 512, 0);
      ln_f32<<<R / 4, 256, 0, stream>>>(Xs, Ac, X, Xh, ln2_g, ln2_b, c, 4095);
      for (long s = 0; s < R; s += Rh) {
        gemm_h<<<dim3(16, Rh / 128), 256, 0, stream>>>(Xh + (c + s) * 512, Wl + 2097152,
                                                       ffn_b1, Hb, (int)Rh, 2048, 512, 3);
        gemm_h<<<dim3(4, Rh / 128), 256, 0, stream>>>(Hb, Wl + 3145728, ffn_b2,
                                                      Ac + s * 512, (int)Rh, 512, 2048, 0);
      }
      ln_f32<<<R / 4, 256, 0, stream>>>(X, Ac, X, Xh, ln3_g, ln3_b, c, 0x7FFFFFFF);
    }
  }
  // =================== layer 1 (x rows = 32768, chunked by R) ===================
  {
    _Float16* Wl = Wh + 4194304;
    gemm_h<<<dim3(4, 8), 256, 0, stream>>>(qh, Wl + 1310720, ca_bk + 512, K0, 1024, 512, 512, 2);
    gemm_h<<<dim3(4, 8), 256, 0, stream>>>(qh, Wl + 1572864, ca_bv + 512, V0, 1024, 512, 512, 2);
    dim3 gR(4, R / 128);
    for (long c = 0; c < 32768; c += R) {
      _Float16* Xhc = Xh + c * 512;
      gemm_h<<<gR, 256, 0, stream>>>(Xhc, Wl + 0,      sa_bq + 512, Qc, (int)R, 512, 512, 2);
      gemm_h<<<gR, 256, 0, stream>>>(Xhc, Wl + 262144, sa_bk + 512, Kc, (int)R, 512, 512, 2);
      gemm_h<<<gR, 256, 0, stream>>>(Xhc, Wl + 524288, sa_bv + 512, Vc, (int)R, 512, 512, 2);
      attn_h<<<(R / 128) * 8, 256, 0, stream>>>(Qc, Kc, Vc, Oc, 0, 0, 0);
      gemm_h<<<gR, 256, 0, stream>>>(Oc, Wl + 786432, sa_bo + 512, Ac, (int)R, 512, 512, 0);
      ln_f32<<<R / 4, 256, 0, stream>>>(X, Ac, X, Xh, ln1_g + 512, ln1_b + 512, c, 0x7FFFFFFF);
      gemm_h<<<gR, 256, 0, stream>>>(Xhc, Wl + 1048576, ca_bq + 512, Qc, (int)R, 512, 512, 2);
      attn_h<<<(R / 128) * 8, 256, 0, stream>>>(Qc, K0, V0, Oc, 1, 0, (int)(c / 128));
      gemm_h<<<gR, 256, 0, stream>>>(Oc, Wl + 1835008, ca_bo + 512, Ac, (int)R, 512, 512, 0);
      ln_f32<<<R / 4, 256, 0, stream>>>(X, Ac, X, Xh, ln2_g + 512, ln2_b + 512, c, 0x7FFFFFFF);
      for (long s = 0; s < R; s += Rh) {
        gemm_h<<<dim3(16, Rh / 128), 256, 0, stream>>>(Xh + (c + s) * 512, Wl + 2097152,
                                                       ffn_b1 + 2048, Hb, (int)Rh, 2048, 512, 3);
        gemm_h<<<dim3(4, Rh / 128), 256, 0, stream>>>(Hb, Wl + 3145728, ffn_b2 + 512,
                                                      Ac + s * 512, (int)Rh, 512, 2048, 0);
      }
      ln_f32<<<R / 4, 256, 0, stream>>>(X, Ac, X, Xh, ln3_g + 512, ln3_b + 512, c, 0x7FFFFFFF);
    }
  }
  // =================== final LN + pooling + features + cosine ===================
  ln_f32<<<8192, 256, 0, stream>>>(X, nullptr, X, nullptr, lnf_g, lnf_b, 0, 0x7FFFFFFF);
  pool_mean<<<256, 256, 0, stream>>>(X, CP);
  pool_mean<<<8, 256, 0, stream>>>(q_in, QP);
  featq_kernel<<<8, 256, 0, stream>>>(QP, feat_wq, feat_bq, QN);
  featc_kernel<<<256, 256, 0, stream>>>(CP, feat_wc, feat_bc, QN, (float*)d_out);
}

// Round 5
// 1920.732 us; speedup vs baseline: 3.5955x; 1.2479x over previous
//
#include <hip/hip_runtime.h>

using half8  = __attribute__((ext_vector_type(8))) _Float16;
using floatx4 = __attribute__((ext_vector_type(4))) float;

__device__ __forceinline__ void gl_lds16(const _Float16* g, _Float16* l)
{
  __builtin_amdgcn_global_load_lds(
      (const __attribute__((address_space(1))) void*)g,
      (__attribute__((address_space(3))) void*)l, 16, 0, 0);
}

// ---------------- MFMA fp16 GEMM: C[M,N](fp16, row stride ldC) = A[M,K] @ Bt[N,K]^T + bias
// Block 256 = 4 waves; 128x128 tile; wave 64x64 via 4x4 MFMA 16x16x32; BK=32.
// Staging via global_load_lds width=16 into unpadded [128][32] tiles.
__global__ __launch_bounds__(256) void gemm_h(
    const _Float16* __restrict__ A, const _Float16* __restrict__ Bt,
    const float* __restrict__ bias, _Float16* __restrict__ C,
    int M, int N, int K, int ldC, int relu)
{
  __shared__ _Float16 As[128 * 32];
  __shared__ _Float16 Bs[128 * 32];
  int tid = threadIdx.x;
  int lane = tid & 63, wave = tid >> 6;
  long bm0 = (long)blockIdx.y * 128;
  int bn0 = blockIdx.x * 128;
  int wm = (wave & 1) * 64, wn = (wave >> 1) * 64;
  int srow = wave * 16 + (lane >> 2);
  int scol = (lane & 3) * 8;
  const _Float16* aA0 = A + (bm0 + srow) * (long)K + scol;
  const _Float16* aA1 = aA0 + 64 * (long)K;
  const _Float16* aB0 = Bt + (bn0 + srow) * (long)K + scol;
  const _Float16* aB1 = aB0 + 64 * (long)K;
  _Float16* lA0 = As + wave * 512;
  _Float16* lA1 = As + 2048 + wave * 512;
  _Float16* lB0 = Bs + wave * 512;
  _Float16* lB1 = Bs + 2048 + wave * 512;
  int mrow = lane & 15, quad = lane >> 4;
  floatx4 acc[4][4];
#pragma unroll
  for (int i = 0; i < 4; ++i)
#pragma unroll
    for (int j = 0; j < 4; ++j) acc[i][j] = (floatx4){0.f, 0.f, 0.f, 0.f};

  for (int kt = 0; kt < K; kt += 32) {
    __syncthreads();
    gl_lds16(aA0 + kt, lA0);
    gl_lds16(aA1 + kt, lA1);
    gl_lds16(aB0 + kt, lB0);
    gl_lds16(aB1 + kt, lB1);
    __syncthreads();
    half8 af[4], bf[4];
#pragma unroll
    for (int i = 0; i < 4; ++i)
      af[i] = *(const half8*)&As[(wm + 16 * i + mrow) * 32 + quad * 8];
#pragma unroll
    for (int j = 0; j < 4; ++j)
      bf[j] = *(const half8*)&Bs[(wn + 16 * j + mrow) * 32 + quad * 8];
#pragma unroll
    for (int i = 0; i < 4; ++i)
#pragma unroll
      for (int j = 0; j < 4; ++j)
        acc[i][j] = __builtin_amdgcn_mfma_f32_16x16x32_f16(af[i], bf[j], acc[i][j], 0, 0, 0);
  }
#pragma unroll
  for (int j = 0; j < 4; ++j) {
    int n = bn0 + wn + 16 * j + mrow;
    float bj = bias[n];
#pragma unroll
    for (int i = 0; i < 4; ++i) {
#pragma unroll
      for (int r = 0; r < 4; ++r) {
        long m = bm0 + wm + 16 * i + quad * 4 + r;
        float v = acc[i][j][r] + bj;
        if (relu) v = fmaxf(v, 0.f);
        C[m * (long)ldC + n] = (_Float16)v;
      }
    }
  }
}

// ---------------- Fused attention (fp16 in/out, fp32 math). One block per (row-block, head).
// Q row stride qs, K/V row stride ks (separate base pointers). O dense [rows][512].
// mode_ca=0: Q,K,V chunk-local at block rl. mode_ca=1: g=rb0+rl=a*32+b; K/V batch a=g>>5
// (1024-row buffer); Q at block (l0 ? g&31 : rl).
__global__ __launch_bounds__(256) void attn_h(
    const _Float16* __restrict__ Qp, int qs,
    const _Float16* __restrict__ Kp, const _Float16* __restrict__ Vp, int ks,
    _Float16* __restrict__ Op, int mode_ca, int l0, int rb0)
{
  __shared__ float Ks[128][68];
  __shared__ float Qs[32][68];
  __shared__ float Ss[32][132];
  __shared__ float rsum[32];
  int idx = blockIdx.x;
  int n = idx & 7;
  int rl = idx >> 3;
  long obase = (long)rl * 128 * 512 + n * 64;
  long qoff, koff;
  if (!mode_ca) {
    qoff = (long)rl * 128 * qs + n * 64;
    koff = (long)rl * 128 * ks + n * 64;
  } else {
    int g = rb0 + rl;
    int a = g >> 5;
    int qblk = l0 ? (g & 31) : rl;
    qoff = (long)qblk * 128 * qs + n * 64;
    koff = (long)a * 128 * ks + n * 64;
  }
  int tid = threadIdx.x;
#pragma unroll
  for (int i = 0; i < 32; ++i) {
    int e = tid + i * 256;
    Ks[e >> 6][e & 63] = (float)Kp[koff + (long)(e >> 6) * ks + (e & 63)];
  }
  int r = tid >> 3, c0 = tid & 7;
  int hlane = tid & 63, rg = tid >> 6;
  for (int ch = 0; ch < 4; ++ch) {
    __syncthreads();
#pragma unroll
    for (int i = 0; i < 8; ++i) {
      int e = tid + i * 256;
      Qs[e >> 6][e & 63] = (float)Qp[qoff + (long)(ch * 32 + (e >> 6)) * qs + (e & 63)];
    }
    __syncthreads();
    float acc[16];
#pragma unroll
    for (int j = 0; j < 16; ++j) acc[j] = 0.f;
    for (int h = 0; h < 64; h += 4) {
      float4 qv = *(const float4*)&Qs[r][h];
#pragma unroll
      for (int j = 0; j < 16; ++j) {
        float4 kv = *(const float4*)&Ks[c0 + j * 8][h];
        acc[j] += qv.x * kv.x + qv.y * kv.y + qv.z * kv.z + qv.w * kv.w;
      }
    }
    float mx = -1e30f;
#pragma unroll
    for (int j = 0; j < 16; ++j) { acc[j] *= 0.125f; mx = fmaxf(mx, acc[j]); }
#pragma unroll
    for (int off = 1; off < 8; off <<= 1) mx = fmaxf(mx, __shfl_xor(mx, off));
    float sum = 0.f;
#pragma unroll
    for (int j = 0; j < 16; ++j) { acc[j] = __expf(acc[j] - mx); sum += acc[j]; }
#pragma unroll
    for (int off = 1; off < 8; off <<= 1) sum += __shfl_xor(sum, off);
#pragma unroll
    for (int j = 0; j < 16; ++j) Ss[r][c0 + 8 * j] = acc[j];
    if (c0 == 0) rsum[r] = sum;
    __syncthreads();
    float ov[8];
#pragma unroll
    for (int i = 0; i < 8; ++i) ov[i] = 0.f;
    for (int k = 0; k < 128; ++k) {
      float v = (float)Vp[koff + (long)k * ks + hlane];
#pragma unroll
      for (int i = 0; i < 8; ++i) ov[i] += Ss[rg + 4 * i][k] * v;
    }
#pragma unroll
    for (int i = 0; i < 8; ++i) {
      int rr = rg + 4 * i;
      Op[obase + (long)(ch * 32 + rr) * 512 + hlane] = (_Float16)(ov[i] / rsum[rr]);
    }
  }
}

// ---------------- Residual + LayerNorm (rows of 512, fp32 math). One wave per row.
// xin fp32 (xf32=1) or fp16; add fp16 chunk-local (or null); out fp16 at row0+rl.
__global__ __launch_bounds__(256) void ln_h(
    const void* __restrict__ xin, int xf32, const _Float16* __restrict__ add,
    _Float16* __restrict__ out, const float* __restrict__ g,
    const float* __restrict__ bt, long row0, int bmask)
{
  int rl = blockIdx.x * 4 + (threadIdx.x >> 6);
  long row = row0 + rl;
  int lane = threadIdx.x & 63;
  long xr = (row & (long)bmask) * 512 + lane * 8;
  float v[8];
  if (xf32) {
    float4 a0 = *(const float4*)((const float*)xin + xr);
    float4 a1 = *(const float4*)((const float*)xin + xr + 4);
    v[0] = a0.x; v[1] = a0.y; v[2] = a0.z; v[3] = a0.w;
    v[4] = a1.x; v[5] = a1.y; v[6] = a1.z; v[7] = a1.w;
  } else {
    half8 h = *(const half8*)((const _Float16*)xin + xr);
#pragma unroll
    for (int i = 0; i < 8; ++i) v[i] = (float)h[i];
  }
  if (add) {
    half8 a = *(const half8*)&add[(long)rl * 512 + lane * 8];
#pragma unroll
    for (int i = 0; i < 8; ++i) v[i] += (float)a[i];
  }
  float s = 0.f, sq = 0.f;
#pragma unroll
  for (int i = 0; i < 8; ++i) { s += v[i]; sq += v[i] * v[i]; }
#pragma unroll
  for (int off = 1; off < 64; off <<= 1) {
    s += __shfl_xor(s, off);
    sq += __shfl_xor(sq, off);
  }
  float mean = s * (1.f / 512.f);
  float var = sq * (1.f / 512.f) - mean * mean;
  float rst = rsqrtf(var + 1e-6f);
  int c = lane * 8;
  float4 g0 = *(const float4*)&g[c], g1 = *(const float4*)&g[c + 4];
  float4 b0 = *(const float4*)&bt[c], b1 = *(const float4*)&bt[c + 4];
  float gg[8] = {g0.x, g0.y, g0.z, g0.w, g1.x, g1.y, g1.z, g1.w};
  float bb[8] = {b0.x, b0.y, b0.z, b0.w, b1.x, b1.y, b1.z, b1.w};
  half8 o;
#pragma unroll
  for (int i = 0; i < 8; ++i) o[i] = (_Float16)((v[i] - mean) * rst * gg[i] + bb[i]);
  *(half8*)&out[row * 512 + c] = o;
}

// ---------------- transpose-convert: in fp32 [Rr][Cc] -> out fp16 [Cc][Rr]
__global__ __launch_bounds__(256) void tconv(const float* __restrict__ in,
                                             _Float16* __restrict__ out, int Rr, int Cc)
{
  __shared__ float T[64][65];
  int tx = threadIdx.x & 63, tg = threadIdx.x >> 6;
  int r0 = blockIdx.y * 64, c0 = blockIdx.x * 64;
#pragma unroll
  for (int i = 0; i < 16; ++i)
    T[tg + 4 * i][tx] = in[(long)(r0 + tg + 4 * i) * Cc + c0 + tx];
  __syncthreads();
#pragma unroll
  for (int i = 0; i < 16; ++i)
    out[(long)(c0 + tg + 4 * i) * Rr + r0 + tx] = (_Float16)T[tx][tg + 4 * i];
}

// ---------------- wo layer slice (8,512,64) fp32 -> Bt[d=512][nh=512] fp16
__global__ void woconv(const float* __restrict__ wo, _Float16* __restrict__ out)
{
  int o = blockIdx.x * 256 + threadIdx.x;  // 262144
  int d = o >> 9;
  int nh = o & 511;
  int n = nh >> 6, h = nh & 63;
  out[o] = (_Float16)wo[((long)(n << 9) + d) * 64 + h];
}

__global__ void f2h(const float* __restrict__ in, _Float16* __restrict__ out, long n)
{
  long i = blockIdx.x * 256L + threadIdx.x;
  if (i < n) out[i] = (_Float16)in[i];
}

__global__ void copyf(const float* __restrict__ s, float* __restrict__ d, int n)
{
  int i = blockIdx.x * 256 + threadIdx.x;
  if (i < n) d[i] = s[i];
}

// ---------------- mean over tokens 1..127 -> [ab, 512]
__global__ void pool_h(const _Float16* __restrict__ X, float* __restrict__ P)
{
  int ab = blockIdx.x;
  for (int dd = threadIdx.x; dd < 512; dd += 256) {
    const _Float16* base = X + (long)ab * 65536 + dd;
    float s = 0.f;
    for (int t = 1; t < 128; ++t) s += (float)base[t * 512];
    P[ab * 512 + dd] = s * (1.f / 127.f);
  }
}

__global__ void pool_f(const float* __restrict__ X, float* __restrict__ P)
{
  int ab = blockIdx.x;
  for (int dd = threadIdx.x; dd < 512; dd += 256) {
    const float* base = X + (long)ab * 65536 + dd;
    float s = 0.f;
    for (int t = 1; t < 128; ++t) s += base[t * 512];
    P[ab * 512 + dd] = s * (1.f / 127.f);
  }
}

__global__ void featq_kernel(const float* __restrict__ QP, const float* __restrict__ W,
                             const float* __restrict__ bias, float* __restrict__ QN)
{
  int a = blockIdx.x;
  int f = threadIdx.x;
  float acc = bias[f];
  const float* xr = QP + a * 512;
  for (int d = 0; d < 512; ++d) acc += xr[d] * W[d * 256 + f];
  __shared__ float red[256];
  red[f] = acc * acc;
  __syncthreads();
  for (int s = 128; s > 0; s >>= 1) {
    if (f < s) red[f] += red[f + s];
    __syncthreads();
  }
  float rn = rsqrtf(fmaxf(red[0], 1e-12f));
  QN[a * 256 + f] = acc * rn;
}

__global__ void featc_kernel(const float* __restrict__ CP, const float* __restrict__ W,
                             const float* __restrict__ bias, const float* __restrict__ QN,
                             float* __restrict__ out)
{
  int ab = blockIdx.x;
  int f = threadIdx.x;
  float acc = bias[f];
  const float* xr = CP + ab * 512;
  for (int d = 0; d < 512; ++d) acc += xr[d] * W[d * 256 + f];
  __shared__ float red[256];
  red[f] = acc * acc;
  __syncthreads();
  for (int s = 128; s > 0; s >>= 1) {
    if (f < s) red[f] += red[f + s];
    __syncthreads();
  }
  float rn = rsqrtf(fmaxf(red[0], 1e-12f));
  float v = acc * rn * QN[(ab >> 5) * 256 + f];
  __syncthreads();
  red[f] = v;
  __syncthreads();
  for (int s = 128; s > 0; s >>= 1) {
    if (f < s) red[f] += red[f + s];
    __syncthreads();
  }
  if (f == 0) out[ab] = red[0];
}

extern "C" void kernel_launch(void* const* d_in, const int* in_sizes, int n_in,
                              void* d_out, int out_size, void* d_ws, size_t ws_size,
                              hipStream_t stream)
{
  (void)in_sizes; (void)n_in; (void)out_size;
  const float* c_in  = (const float*)d_in[0];
  const float* q_in  = (const float*)d_in[1];
  const float* sa_wq = (const float*)d_in[2];
  const float* sa_bq = (const float*)d_in[3];
  const float* sa_wk = (const float*)d_in[4];
  const float* sa_bk = (const float*)d_in[5];
  const float* sa_wv = (const float*)d_in[6];
  const float* sa_bv = (const float*)d_in[7];
  const float* sa_wo = (const float*)d_in[8];
  const float* sa_bo = (const float*)d_in[9];
  const float* ca_wq = (const float*)d_in[10];
  const float* ca_bq = (const float*)d_in[11];
  const float* ca_wk = (const float*)d_in[12];
  const float* ca_bk = (const float*)d_in[13];
  const float* ca_wv = (const float*)d_in[14];
  const float* ca_bv = (const float*)d_in[15];
  const float* ca_wo = (const float*)d_in[16];
  const float* ca_bo = (const float*)d_in[17];
  const float* ln1_g = (const float*)d_in[18];
  const float* ln1_b = (const float*)d_in[19];
  const float* ln2_g = (const float*)d_in[20];
  const float* ln2_b = (const float*)d_in[21];
  const float* ln3_g = (const float*)d_in[22];
  const float* ln3_b = (const float*)d_in[23];
  const float* ffn_w1 = (const float*)d_in[24];
  const float* ffn_b1 = (const float*)d_in[25];
  const float* ffn_w2 = (const float*)d_in[26];
  const float* ffn_b2 = (const float*)d_in[27];
  const float* lnf_g  = (const float*)d_in[28];
  const float* lnf_b  = (const float*)d_in[29];
  const float* feat_wq = (const float*)d_in[30];
  const float* feat_bq = (const float*)d_in[31];
  const float* feat_wc = (const float*)d_in[32];
  const float* feat_bc = (const float*)d_in[33];

  // ---- workspace layout, fp16 residual stream; ws-adaptive chunk R
  char* p = (char*)d_ws;
  _Float16* Xh  = (_Float16*)p;  p += 33554432;  // 32768 x 512 fp16 residual stream
  _Float16* Xsh = (_Float16*)p;  p += 4194304;   //  4096 x 512 fp16 (layer-0 x / c fp16)
  _Float16* Wh  = (_Float16*)p;  p += 16777216;  // fused fp16 weight arena (2 layers)
  _Float16* qh  = (_Float16*)p;  p += 1048576;   //  1024 x 512 fp16
  _Float16* KV0 = (_Float16*)p;  p += 2097152;   //  1024 x 1024 fp16 (K|V parts)
  float*    Bqkv = (float*)p;    p += 12288;     // 2 x 1536 packed QKV bias
  float*    Bkv  = (float*)p;    p += 8192;      // 2 x 1024 packed CA-KV bias
  float*    CP  = (float*)p;     p += 524288;
  float*    QP  = (float*)p;     p += 16384;
  float*    QN  = (float*)p;     p += 8192;
  const size_t fixed_b = (size_t)(p - (char*)d_ws);
  long R = 4096;
  if (ws_size >= fixed_b + 5120UL * 32768) R = 32768;
  else if (ws_size >= fixed_b + 5120UL * 16384) R = 16384;
  else if (ws_size >= fixed_b + 5120UL * 8192) R = 8192;
  _Float16* QKVc = (_Float16*)p; p += R * 3072;  // [R][1536] Q|K|V
  _Float16* Oc   = (_Float16*)p; p += R * 1024;  // [R][512]
  _Float16* Ac   = (_Float16*)p;                 // [R][512] residual-add input
  _Float16* Hb = QKVc;           // FFN hidden [R/2][2048] aliases QKVc
  const long Rh = R / 2;

  // ---- prep
  f2h<<<8192, 256, 0, stream>>>(c_in, Xsh, 2097152);
  f2h<<<2048, 256, 0, stream>>>(q_in, qh, 524288);
  for (int l = 0; l < 2; ++l) {
    _Float16* Wl = Wh + (long)l * 4194304;
    long woff = (long)l * 262144;
    tconv<<<dim3(8, 8), 256, 0, stream>>>(sa_wq + woff, Wl + 0, 512, 512);
    tconv<<<dim3(8, 8), 256, 0, stream>>>(sa_wk + woff, Wl + 262144, 512, 512);
    tconv<<<dim3(8, 8), 256, 0, stream>>>(sa_wv + woff, Wl + 524288, 512, 512);
    woconv<<<1024, 256, 0, stream>>>(sa_wo + woff, Wl + 786432);
    tconv<<<dim3(8, 8), 256, 0, stream>>>(ca_wq + woff, Wl + 1048576, 512, 512);
    tconv<<<dim3(8, 8), 256, 0, stream>>>(ca_wk + woff, Wl + 1310720, 512, 512);
    tconv<<<dim3(8, 8), 256, 0, stream>>>(ca_wv + woff, Wl + 1572864, 512, 512);
    woconv<<<1024, 256, 0, stream>>>(ca_wo + woff, Wl + 1835008);
    tconv<<<dim3(32, 8), 256, 0, stream>>>(ffn_w1 + (long)l * 1048576, Wl + 2097152, 512, 2048);
    tconv<<<dim3(8, 32), 256, 0, stream>>>(ffn_w2 + (long)l * 1048576, Wl + 3145728, 2048, 512);
    copyf<<<2, 256, 0, stream>>>(sa_bq + l * 512, Bqkv + l * 1536, 512);
    copyf<<<2, 256, 0, stream>>>(sa_bk + l * 512, Bqkv + l * 1536 + 512, 512);
    copyf<<<2, 256, 0, stream>>>(sa_bv + l * 512, Bqkv + l * 1536 + 1024, 512);
    copyf<<<2, 256, 0, stream>>>(ca_bk + l * 512, Bkv + l * 1024, 512);
    copyf<<<2, 256, 0, stream>>>(ca_bv + l * 512, Bkv + l * 1024 + 512, 512);
  }

  // =================== layer 0 (x rows = 4096) ===================
  {
    _Float16* Wl = Wh;
    gemm_h<<<dim3(12, 32), 256, 0, stream>>>(Xsh, Wl + 0, Bqkv, QKVc, 4096, 1536, 512, 1536, 0);
    attn_h<<<256, 256, 0, stream>>>(QKVc, 1536, QKVc + 512, QKVc + 1024, 1536, Oc, 0, 0, 0);
    gemm_h<<<dim3(4, 32), 256, 0, stream>>>(Oc, Wl + 786432, sa_bo, Ac, 4096, 512, 512, 512, 0);
    ln_h<<<1024, 256, 0, stream>>>(c_in, 1, Ac, Xsh, ln1_g, ln1_b, 0, 0x7FFFFFFF);
    gemm_h<<<dim3(4, 32), 256, 0, stream>>>(Xsh, Wl + 1048576, ca_bq, QKVc, 4096, 512, 512, 1536, 0);
    gemm_h<<<dim3(8, 8), 256, 0, stream>>>(qh, Wl + 1310720, Bkv, KV0, 1024, 1024, 512, 1024, 0);
    for (long c = 0; c < 32768; c += R) {
      attn_h<<<(R / 128) * 8, 256, 0, stream>>>(QKVc, 1536, KV0, KV0 + 512, 1024, Oc,
                                                1, 1, (int)(c / 128));
      gemm_h<<<dim3(4, R / 128), 256, 0, stream>>>(Oc, Wl + 1835008, ca_bo, Ac,
                                                   (int)R, 512, 512, 512, 0);
      ln_h<<<R / 4, 256, 0, stream>>>(Xsh, 0, Ac, Xh, ln2_g, ln2_b, c, 4095);
      for (long s = 0; s < R; s += Rh) {
        gemm_h<<<dim3(16, Rh / 128), 256, 0, stream>>>(Xh + (c + s) * 512, Wl + 2097152,
                                                       ffn_b1, Hb, (int)Rh, 2048, 512, 2048, 1);
        gemm_h<<<dim3(4, Rh / 128), 256, 0, stream>>>(Hb, Wl + 3145728, ffn_b2,
                                                      Ac + s * 512, (int)Rh, 512, 2048, 512, 0);
      }
      ln_h<<<R / 4, 256, 0, stream>>>(Xh, 0, Ac, Xh, ln3_g, ln3_b, c, 0x7FFFFFFF);
    }
  }
  // =================== layer 1 (x rows = 32768, chunked by R) ===================
  {
    _Float16* Wl = Wh + 4194304;
    gemm_h<<<dim3(8, 8), 256, 0, stream>>>(qh, Wl + 1310720, Bkv + 1024, KV0, 1024, 1024, 512, 1024, 0);
    for (long c = 0; c < 32768; c += R) {
      _Float16* Xhc = Xh + c * 512;
      gemm_h<<<dim3(12, R / 128), 256, 0, stream>>>(Xhc, Wl + 0, Bqkv + 1536, QKVc,
                                                    (int)R, 1536, 512, 1536, 0);
      attn_h<<<(R / 128) * 8, 256, 0, stream>>>(QKVc, 1536, QKVc + 512, QKVc + 1024, 1536,
                                                Oc, 0, 0, 0);
      gemm_h<<<dim3(4, R / 128), 256, 0, stream>>>(Oc, Wl + 786432, sa_bo + 512, Ac,
                                                   (int)R, 512, 512, 512, 0);
      ln_h<<<R / 4, 256, 0, stream>>>(Xh, 0, Ac, Xh, ln1_g + 512, ln1_b + 512, c, 0x7FFFFFFF);
      gemm_h<<<dim3(4, R / 128), 256, 0, stream>>>(Xhc, Wl + 1048576, ca_bq + 512, QKVc,
                                                   (int)R, 512, 512, 1536, 0);
      attn_h<<<(R / 128) * 8, 256, 0, stream>>>(QKVc, 1536, KV0, KV0 + 512, 1024, Oc,
                                                1, 0, (int)(c / 128));
      gemm_h<<<dim3(4, R / 128), 256, 0, stream>>>(Oc, Wl + 1835008, ca_bo + 512, Ac,
                                                   (int)R, 512, 512, 512, 0);
      ln_h<<<R / 4, 256, 0, stream>>>(Xh, 0, Ac, Xh, ln2_g + 512, ln2_b + 512, c, 0x7FFFFFFF);
      for (long s = 0; s < R; s += Rh) {
        gemm_h<<<dim3(16, Rh / 128), 256, 0, stream>>>(Xh + (c + s) * 512, Wl + 2097152,
                                                       ffn_b1 + 2048, Hb, (int)Rh, 2048, 512, 2048, 1);
        gemm_h<<<dim3(4, Rh / 128), 256, 0, stream>>>(Hb, Wl + 3145728, ffn_b2 + 512,
                                                      Ac + s * 512, (int)Rh, 512, 2048, 512, 0);
      }
      ln_h<<<R / 4, 256, 0, stream>>>(Xh, 0, Ac, Xh, ln3_g + 512, ln3_b + 512, c, 0x7FFFFFFF);
    }
  }
  // =================== final LN + pooling + features + cosine ===================
  ln_h<<<8192, 256, 0, stream>>>(Xh, 0, nullptr, Xh, lnf_g, lnf_b, 0, 0x7FFFFFFF);
  pool_h<<<256, 256, 0, stream>>>(Xh, CP);
  pool_f<<<8, 256, 0, stream>>>(q_in, QP);
  featq_kernel<<<8, 256, 0, stream>>>(QP, feat_wq, feat_bq, QN);
  featc_kernel<<<256, 256, 0, stream>>>(CP, feat_wc, feat_bc, QN, (float*)d_out);
}

// Round 6
// 1236.412 us; speedup vs baseline: 5.5856x; 1.5535x over previous
//
#include <hip/hip_runtime.h>

using half4  = __attribute__((ext_vector_type(4))) _Float16;
using half8  = __attribute__((ext_vector_type(8))) _Float16;
using floatx4 = __attribute__((ext_vector_type(4))) float;

__device__ __forceinline__ void gl_lds16(const _Float16* g, _Float16* l)
{
  __builtin_amdgcn_global_load_lds(
      (const __attribute__((address_space(1))) void*)g,
      (__attribute__((address_space(3))) void*)l, 16, 0, 0);
}

// ---------------- MFMA fp16 GEMM: C[M,N](fp16, row stride ldC) = A[M,K] @ Bt[N,K]^T + bias
// Block 256 = 4 waves; 128x128 tile; wave 64x64 via 4x4 MFMA 16x16x32; BK=32.
__global__ __launch_bounds__(256) void gemm_h(
    const _Float16* __restrict__ A, const _Float16* __restrict__ Bt,
    const float* __restrict__ bias, _Float16* __restrict__ C,
    int M, int N, int K, int ldC, int relu)
{
  __shared__ _Float16 As[128 * 32];
  __shared__ _Float16 Bs[128 * 32];
  int tid = threadIdx.x;
  int lane = tid & 63, wave = tid >> 6;
  long bm0 = (long)blockIdx.y * 128;
  int bn0 = blockIdx.x * 128;
  int wm = (wave & 1) * 64, wn = (wave >> 1) * 64;
  int srow = wave * 16 + (lane >> 2);
  int scol = (lane & 3) * 8;
  const _Float16* aA0 = A + (bm0 + srow) * (long)K + scol;
  const _Float16* aA1 = aA0 + 64 * (long)K;
  const _Float16* aB0 = Bt + (bn0 + srow) * (long)K + scol;
  const _Float16* aB1 = aB0 + 64 * (long)K;
  _Float16* lA0 = As + wave * 512;
  _Float16* lA1 = As + 2048 + wave * 512;
  _Float16* lB0 = Bs + wave * 512;
  _Float16* lB1 = Bs + 2048 + wave * 512;
  int mrow = lane & 15, quad = lane >> 4;
  floatx4 acc[4][4];
#pragma unroll
  for (int i = 0; i < 4; ++i)
#pragma unroll
    for (int j = 0; j < 4; ++j) acc[i][j] = (floatx4){0.f, 0.f, 0.f, 0.f};

  for (int kt = 0; kt < K; kt += 32) {
    __syncthreads();
    gl_lds16(aA0 + kt, lA0);
    gl_lds16(aA1 + kt, lA1);
    gl_lds16(aB0 + kt, lB0);
    gl_lds16(aB1 + kt, lB1);
    __syncthreads();
    half8 af[4], bf[4];
#pragma unroll
    for (int i = 0; i < 4; ++i)
      af[i] = *(const half8*)&As[(wm + 16 * i + mrow) * 32 + quad * 8];
#pragma unroll
    for (int j = 0; j < 4; ++j)
      bf[j] = *(const half8*)&Bs[(wn + 16 * j + mrow) * 32 + quad * 8];
#pragma unroll
    for (int i = 0; i < 4; ++i)
#pragma unroll
      for (int j = 0; j < 4; ++j)
        acc[i][j] = __builtin_amdgcn_mfma_f32_16x16x32_f16(af[i], bf[j], acc[i][j], 0, 0, 0);
  }
#pragma unroll
  for (int j = 0; j < 4; ++j) {
    int n = bn0 + wn + 16 * j + mrow;
    float bj = bias[n];
#pragma unroll
    for (int i = 0; i < 4; ++i) {
#pragma unroll
      for (int r = 0; r < 4; ++r) {
        long m = bm0 + wm + 16 * i + quad * 4 + r;
        float v = acc[i][j][r] + bj;
        if (relu) v = fmaxf(v, 0.f);
        C[m * (long)ldC + n] = (_Float16)v;
      }
    }
  }
}

// ---------------- MFMA fused attention. One block (4 waves) per (row-block, head).
// S = 128x128 (one exact softmax pass, no online rescale), O = 128x64.
// Wave owns a 32-row Q slab. K staged in LDS [128][72]; V transposed into the
// same region afterwards as Vt[64][132]; P round-trips LDS [128][136] (fp16).
// mode_ca=0: Q,K,V chunk-local at block rl. mode_ca=1: g=rb0+rl=a*32+b; K/V batch
// a=g>>5 (1024-row buffer); Q at block (l0 ? g&31 : rl).
__global__ __launch_bounds__(256) void attn_h(
    const _Float16* __restrict__ Qp, int qs,
    const _Float16* __restrict__ Kp, const _Float16* __restrict__ Vp, int ks,
    _Float16* __restrict__ Op, int mode_ca, int l0, int rb0)
{
  __shared__ _Float16 KV[128 * 72];    // K (stride 72) then Vt (64 x stride 132)
  __shared__ _Float16 Ps[128 * 136];   // P fp16, stride 136 (272B, 16B-aligned)
  int tid = threadIdx.x;
  int lane = tid & 63, wave = tid >> 6;
  int ll = lane & 15, quad = lane >> 4;
  int idx = blockIdx.x;
  int n = idx & 7;
  int rl = idx >> 3;
  long obase = (long)rl * 128 * 512 + n * 64;
  long qoff, koff;
  if (!mode_ca) {
    qoff = (long)rl * 128 * qs + n * 64;
    koff = (long)rl * 128 * ks + n * 64;
  } else {
    int g = rb0 + rl;
    int a = g >> 5;
    int qblk = l0 ? (g & 31) : rl;
    qoff = (long)qblk * 128 * qs + n * 64;
    koff = (long)a * 128 * ks + n * 64;
  }
  // ---- stage K tile [128][64] -> KV stride 72 (vector half8)
#pragma unroll
  for (int it = 0; it < 4; ++it) {
    int e = tid + it * 256;
    int r = e >> 3, c = (e & 7) * 8;
    *(half8*)&KV[r * 72 + c] = *(const half8*)&Kp[koff + (long)r * ks + c];
  }
  // ---- Q fragments straight from global (wave's 32 rows)
  half8 aQ[2][2];
#pragma unroll
  for (int i = 0; i < 2; ++i)
#pragma unroll
    for (int k2 = 0; k2 < 2; ++k2)
      aQ[i][k2] = *(const half8*)&Qp[qoff + (long)(wave * 32 + i * 16 + ll) * qs
                                     + quad * 8 + k2 * 32];
  __syncthreads();
  // ---- S = Q K^T : accS[i][j] tile (rows i*16, cols j*16), C layout
  floatx4 accS[2][8];
#pragma unroll
  for (int i = 0; i < 2; ++i)
#pragma unroll
    for (int j = 0; j < 8; ++j) accS[i][j] = (floatx4){0.f, 0.f, 0.f, 0.f};
#pragma unroll
  for (int k2 = 0; k2 < 2; ++k2) {
#pragma unroll
    for (int j = 0; j < 8; ++j) {
      half8 bK = *(const half8*)&KV[(j * 16 + ll) * 72 + quad * 8 + k2 * 32];
      accS[0][j] = __builtin_amdgcn_mfma_f32_16x16x32_f16(aQ[0][k2], bK, accS[0][j], 0, 0, 0);
      accS[1][j] = __builtin_amdgcn_mfma_f32_16x16x32_f16(aQ[1][k2], bK, accS[1][j], 0, 0, 0);
    }
  }
  // ---- softmax per row (rows = quad*4+r within tile i); cross-lane over 16-group
  float rinv[2][4];
#pragma unroll
  for (int i = 0; i < 2; ++i) {
#pragma unroll
    for (int r = 0; r < 4; ++r) {
      float mx = -1e30f;
#pragma unroll
      for (int j = 0; j < 8; ++j) {
        accS[i][j][r] *= 0.125f;
        mx = fmaxf(mx, accS[i][j][r]);
      }
#pragma unroll
      for (int off = 1; off < 16; off <<= 1) mx = fmaxf(mx, __shfl_xor(mx, off));
      float s = 0.f;
#pragma unroll
      for (int j = 0; j < 8; ++j) {
        float e = __expf(accS[i][j][r] - mx);
        accS[i][j][r] = e;
        s += e;
      }
#pragma unroll
      for (int off = 1; off < 16; off <<= 1) s += __shfl_xor(s, off);
      rinv[i][r] = 1.f / s;
      int prow = wave * 32 + i * 16 + quad * 4 + r;
#pragma unroll
      for (int j = 0; j < 8; ++j)
        Ps[prow * 136 + j * 16 + ll] = (_Float16)accS[i][j][r];
    }
  }
  __syncthreads();   // all waves done reading K region; Ps writes drained past barrier
  // ---- stage V transposed: Vt[h][n] at KV[h*132 + n]
#pragma unroll
  for (int it = 0; it < 4; ++it) {
    int e = tid + it * 256;
    int vr = e >> 3, c = (e & 7) * 8;
    half8 v = *(const half8*)&Vp[koff + (long)vr * ks + c];
#pragma unroll
    for (int j = 0; j < 8; ++j) KV[(c + j) * 132 + vr] = v[j];
  }
  __syncthreads();
  // ---- O = P V : accO[i][jh], k over 128 in 4 steps
  floatx4 accO[2][4];
#pragma unroll
  for (int i = 0; i < 2; ++i)
#pragma unroll
    for (int j = 0; j < 4; ++j) accO[i][j] = (floatx4){0.f, 0.f, 0.f, 0.f};
#pragma unroll
  for (int k4 = 0; k4 < 4; ++k4) {
    half8 aP[2];
#pragma unroll
    for (int i = 0; i < 2; ++i)
      aP[i] = *(const half8*)&Ps[(wave * 32 + i * 16 + ll) * 136 + quad * 8 + k4 * 32];
#pragma unroll
    for (int jh = 0; jh < 4; ++jh) {
      int vb = (jh * 16 + ll) * 132 + quad * 8 + k4 * 32;
      half4 v0 = *(const half4*)&KV[vb];
      half4 v1 = *(const half4*)&KV[vb + 4];
      half8 bV = __builtin_shufflevector(v0, v1, 0, 1, 2, 3, 4, 5, 6, 7);
      accO[0][jh] = __builtin_amdgcn_mfma_f32_16x16x32_f16(aP[0], bV, accO[0][jh], 0, 0, 0);
      accO[1][jh] = __builtin_amdgcn_mfma_f32_16x16x32_f16(aP[1], bV, accO[1][jh], 0, 0, 0);
    }
  }
  // ---- epilogue: scale by 1/rowsum, store fp16
#pragma unroll
  for (int i = 0; i < 2; ++i)
#pragma unroll
    for (int jh = 0; jh < 4; ++jh)
#pragma unroll
      for (int r = 0; r < 4; ++r) {
        int m = wave * 32 + i * 16 + quad * 4 + r;
        Op[obase + (long)m * 512 + jh * 16 + ll] = (_Float16)(accO[i][jh][r] * rinv[i][r]);
      }
}

// ---------------- Residual + LayerNorm (rows of 512, fp32 math). One wave per row.
__global__ __launch_bounds__(256) void ln_h(
    const void* __restrict__ xin, int xf32, const _Float16* __restrict__ add,
    _Float16* __restrict__ out, const float* __restrict__ g,
    const float* __restrict__ bt, long row0, int bmask)
{
  int rl = blockIdx.x * 4 + (threadIdx.x >> 6);
  long row = row0 + rl;
  int lane = threadIdx.x & 63;
  long xr = (row & (long)bmask) * 512 + lane * 8;
  float v[8];
  if (xf32) {
    float4 a0 = *(const float4*)((const float*)xin + xr);
    float4 a1 = *(const float4*)((const float*)xin + xr + 4);
    v[0] = a0.x; v[1] = a0.y; v[2] = a0.z; v[3] = a0.w;
    v[4] = a1.x; v[5] = a1.y; v[6] = a1.z; v[7] = a1.w;
  } else {
    half8 h = *(const half8*)((const _Float16*)xin + xr);
#pragma unroll
    for (int i = 0; i < 8; ++i) v[i] = (float)h[i];
  }
  if (add) {
    half8 a = *(const half8*)&add[(long)rl * 512 + lane * 8];
#pragma unroll
    for (int i = 0; i < 8; ++i) v[i] += (float)a[i];
  }
  float s = 0.f, sq = 0.f;
#pragma unroll
  for (int i = 0; i < 8; ++i) { s += v[i]; sq += v[i] * v[i]; }
#pragma unroll
  for (int off = 1; off < 64; off <<= 1) {
    s += __shfl_xor(s, off);
    sq += __shfl_xor(sq, off);
  }
  float mean = s * (1.f / 512.f);
  float var = sq * (1.f / 512.f) - mean * mean;
  float rst = rsqrtf(var + 1e-6f);
  int c = lane * 8;
  float4 g0 = *(const float4*)&g[c], g1 = *(const float4*)&g[c + 4];
  float4 b0 = *(const float4*)&bt[c], b1 = *(const float4*)&bt[c + 4];
  float gg[8] = {g0.x, g0.y, g0.z, g0.w, g1.x, g1.y, g1.z, g1.w};
  float bb[8] = {b0.x, b0.y, b0.z, b0.w, b1.x, b1.y, b1.z, b1.w};
  half8 o;
#pragma unroll
  for (int i = 0; i < 8; ++i) o[i] = (_Float16)((v[i] - mean) * rst * gg[i] + bb[i]);
  *(half8*)&out[row * 512 + c] = o;
}

// ---------------- transpose-convert: in fp32 [Rr][Cc] -> out fp16 [Cc][Rr]
__global__ __launch_bounds__(256) void tconv(const float* __restrict__ in,
                                             _Float16* __restrict__ out, int Rr, int Cc)
{
  __shared__ float T[64][65];
  int tx = threadIdx.x & 63, tg = threadIdx.x >> 6;
  int r0 = blockIdx.y * 64, c0 = blockIdx.x * 64;
#pragma unroll
  for (int i = 0; i < 16; ++i)
    T[tg + 4 * i][tx] = in[(long)(r0 + tg + 4 * i) * Cc + c0 + tx];
  __syncthreads();
#pragma unroll
  for (int i = 0; i < 16; ++i)
    out[(long)(c0 + tg + 4 * i) * Rr + r0 + tx] = (_Float16)T[tx][tg + 4 * i];
}

// ---------------- wo layer slice (8,512,64) fp32 -> Bt[d=512][nh=512] fp16
__global__ void woconv(const float* __restrict__ wo, _Float16* __restrict__ out)
{
  int o = blockIdx.x * 256 + threadIdx.x;  // 262144
  int d = o >> 9;
  int nh = o & 511;
  int n = nh >> 6, h = nh & 63;
  out[o] = (_Float16)wo[((long)(n << 9) + d) * 64 + h];
}

__global__ void f2h(const float* __restrict__ in, _Float16* __restrict__ out, long n)
{
  long i = blockIdx.x * 256L + threadIdx.x;
  if (i < n) out[i] = (_Float16)in[i];
}

__global__ void copyf(const float* __restrict__ s, float* __restrict__ d, int n)
{
  int i = blockIdx.x * 256 + threadIdx.x;
  if (i < n) d[i] = s[i];
}

// ---------------- mean over tokens 1..127 -> [ab, 512]
__global__ void pool_h(const _Float16* __restrict__ X, float* __restrict__ P)
{
  int ab = blockIdx.x;
  for (int dd = threadIdx.x; dd < 512; dd += 256) {
    const _Float16* base = X + (long)ab * 65536 + dd;
    float s = 0.f;
    for (int t = 1; t < 128; ++t) s += (float)base[t * 512];
    P[ab * 512 + dd] = s * (1.f / 127.f);
  }
}

__global__ void pool_f(const float* __restrict__ X, float* __restrict__ P)
{
  int ab = blockIdx.x;
  for (int dd = threadIdx.x; dd < 512; dd += 256) {
    const float* base = X + (long)ab * 65536 + dd;
    float s = 0.f;
    for (int t = 1; t < 128; ++t) s += base[t * 512];
    P[ab * 512 + dd] = s * (1.f / 127.f);
  }
}

__global__ void featq_kernel(const float* __restrict__ QP, const float* __restrict__ W,
                             const float* __restrict__ bias, float* __restrict__ QN)
{
  int a = blockIdx.x;
  int f = threadIdx.x;
  float acc = bias[f];
  const float* xr = QP + a * 512;
  for (int d = 0; d < 512; ++d) acc += xr[d] * W[d * 256 + f];
  __shared__ float red[256];
  red[f] = acc * acc;
  __syncthreads();
  for (int s = 128; s > 0; s >>= 1) {
    if (f < s) red[f] += red[f + s];
    __syncthreads();
  }
  float rn = rsqrtf(fmaxf(red[0], 1e-12f));
  QN[a * 256 + f] = acc * rn;
}

__global__ void featc_kernel(const float* __restrict__ CP, const float* __restrict__ W,
                             const float* __restrict__ bias, const float* __restrict__ QN,
                             float* __restrict__ out)
{
  int ab = blockIdx.x;
  int f = threadIdx.x;
  float acc = bias[f];
  const float* xr = CP + ab * 512;
  for (int d = 0; d < 512; ++d) acc += xr[d] * W[d * 256 + f];
  __shared__ float red[256];
  red[f] = acc * acc;
  __syncthreads();
  for (int s = 128; s > 0; s >>= 1) {
    if (f < s) red[f] += red[f + s];
    __syncthreads();
  }
  float rn = rsqrtf(fmaxf(red[0], 1e-12f));
  float v = acc * rn * QN[(ab >> 5) * 256 + f];
  __syncthreads();
  red[f] = v;
  __syncthreads();
  for (int s = 128; s > 0; s >>= 1) {
    if (f < s) red[f] += red[f + s];
    __syncthreads();
  }
  if (f == 0) out[ab] = red[0];
}

extern "C" void kernel_launch(void* const* d_in, const int* in_sizes, int n_in,
                              void* d_out, int out_size, void* d_ws, size_t ws_size,
                              hipStream_t stream)
{
  (void)in_sizes; (void)n_in; (void)out_size;
  const float* c_in  = (const float*)d_in[0];
  const float* q_in  = (const float*)d_in[1];
  const float* sa_wq = (const float*)d_in[2];
  const float* sa_bq = (const float*)d_in[3];
  const float* sa_wk = (const float*)d_in[4];
  const float* sa_bk = (const float*)d_in[5];
  const float* sa_wv = (const float*)d_in[6];
  const float* sa_bv = (const float*)d_in[7];
  const float* sa_wo = (const float*)d_in[8];
  const float* sa_bo = (const float*)d_in[9];
  const float* ca_wq = (const float*)d_in[10];
  const float* ca_bq = (const float*)d_in[11];
  const float* ca_wk = (const float*)d_in[12];
  const float* ca_bk = (const float*)d_in[13];
  const float* ca_wv = (const float*)d_in[14];
  const float* ca_bv = (const float*)d_in[15];
  const float* ca_wo = (const float*)d_in[16];
  const float* ca_bo = (const float*)d_in[17];
  const float* ln1_g = (const float*)d_in[18];
  const float* ln1_b = (const float*)d_in[19];
  const float* ln2_g = (const float*)d_in[20];
  const float* ln2_b = (const float*)d_in[21];
  const float* ln3_g = (const float*)d_in[22];
  const float* ln3_b = (const float*)d_in[23];
  const float* ffn_w1 = (const float*)d_in[24];
  const float* ffn_b1 = (const float*)d_in[25];
  const float* ffn_w2 = (const float*)d_in[26];
  const float* ffn_b2 = (const float*)d_in[27];
  const float* lnf_g  = (const float*)d_in[28];
  const float* lnf_b  = (const float*)d_in[29];
  const float* feat_wq = (const float*)d_in[30];
  const float* feat_bq = (const float*)d_in[31];
  const float* feat_wc = (const float*)d_in[32];
  const float* feat_bc = (const float*)d_in[33];

  // ---- workspace layout, fp16 residual stream; ws-adaptive chunk R
  char* p = (char*)d_ws;
  _Float16* Xh  = (_Float16*)p;  p += 33554432;  // 32768 x 512 fp16 residual stream
  _Float16* Xsh = (_Float16*)p;  p += 4194304;   //  4096 x 512 fp16 (layer-0 x)
  _Float16* Wh  = (_Float16*)p;  p += 16777216;  // fused fp16 weight arena (2 layers)
  _Float16* qh  = (_Float16*)p;  p += 1048576;   //  1024 x 512 fp16
  _Float16* KV0 = (_Float16*)p;  p += 2097152;   //  1024 x 1024 fp16 (K|V parts)
  float*    Bqkv = (float*)p;    p += 12288;     // 2 x 1536 packed QKV bias
  float*    Bkv  = (float*)p;    p += 8192;      // 2 x 1024 packed CA-KV bias
  float*    CP  = (float*)p;     p += 524288;
  float*    QP  = (float*)p;     p += 16384;
  float*    QN  = (float*)p;     p += 8192;
  const size_t fixed_b = (size_t)(p - (char*)d_ws);
  long R = 4096;
  if (ws_size >= fixed_b + 5120UL * 32768) R = 32768;
  else if (ws_size >= fixed_b + 5120UL * 16384) R = 16384;
  else if (ws_size >= fixed_b + 5120UL * 8192) R = 8192;
  _Float16* QKVc = (_Float16*)p; p += R * 3072;  // [R][1536] Q|K|V
  _Float16* Oc   = (_Float16*)p; p += R * 1024;  // [R][512]
  _Float16* Ac   = (_Float16*)p;                 // [R][512] residual-add input
  _Float16* Hb = QKVc;           // FFN hidden [R/2][2048] aliases QKVc
  const long Rh = R / 2;

  // ---- prep
  f2h<<<8192, 256, 0, stream>>>(c_in, Xsh, 2097152);
  f2h<<<2048, 256, 0, stream>>>(q_in, qh, 524288);
  for (int l = 0; l < 2; ++l) {
    _Float16* Wl = Wh + (long)l * 4194304;
    long woff = (long)l * 262144;
    tconv<<<dim3(8, 8), 256, 0, stream>>>(sa_wq + woff, Wl + 0, 512, 512);
    tconv<<<dim3(8, 8), 256, 0, stream>>>(sa_wk + woff, Wl + 262144, 512, 512);
    tconv<<<dim3(8, 8), 256, 0, stream>>>(sa_wv + woff, Wl + 524288, 512, 512);
    woconv<<<1024, 256, 0, stream>>>(sa_wo + woff, Wl + 786432);
    tconv<<<dim3(8, 8), 256, 0, stream>>>(ca_wq + woff, Wl + 1048576, 512, 512);
    tconv<<<dim3(8, 8), 256, 0, stream>>>(ca_wk + woff, Wl + 1310720, 512, 512);
    tconv<<<dim3(8, 8), 256, 0, stream>>>(ca_wv + woff, Wl + 1572864, 512, 512);
    woconv<<<1024, 256, 0, stream>>>(ca_wo + woff, Wl + 1835008);
    tconv<<<dim3(32, 8), 256, 0, stream>>>(ffn_w1 + (long)l * 1048576, Wl + 2097152, 512, 2048);
    tconv<<<dim3(8, 32), 256, 0, stream>>>(ffn_w2 + (long)l * 1048576, Wl + 3145728, 2048, 512);
    copyf<<<2, 256, 0, stream>>>(sa_bq + l * 512, Bqkv + l * 1536, 512);
    copyf<<<2, 256, 0, stream>>>(sa_bk + l * 512, Bqkv + l * 1536 + 512, 512);
    copyf<<<2, 256, 0, stream>>>(sa_bv + l * 512, Bqkv + l * 1536 + 1024, 512);
    copyf<<<2, 256, 0, stream>>>(ca_bk + l * 512, Bkv + l * 1024, 512);
    copyf<<<2, 256, 0, stream>>>(ca_bv + l * 512, Bkv + l * 1024 + 512, 512);
  }

  // =================== layer 0 (x rows = 4096) ===================
  {
    _Float16* Wl = Wh;
    gemm_h<<<dim3(12, 32), 256, 0, stream>>>(Xsh, Wl + 0, Bqkv, QKVc, 4096, 1536, 512, 1536, 0);
    attn_h<<<256, 256, 0, stream>>>(QKVc, 1536, QKVc + 512, QKVc + 1024, 1536, Oc, 0, 0, 0);
    gemm_h<<<dim3(4, 32), 256, 0, stream>>>(Oc, Wl + 786432, sa_bo, Ac, 4096, 512, 512, 512, 0);
    ln_h<<<1024, 256, 0, stream>>>(c_in, 1, Ac, Xsh, ln1_g, ln1_b, 0, 0x7FFFFFFF);
    gemm_h<<<dim3(4, 32), 256, 0, stream>>>(Xsh, Wl + 1048576, ca_bq, QKVc, 4096, 512, 512, 1536, 0);
    gemm_h<<<dim3(8, 8), 256, 0, stream>>>(qh, Wl + 1310720, Bkv, KV0, 1024, 1024, 512, 1024, 0);
    for (long c = 0; c < 32768; c += R) {
      attn_h<<<(R / 128) * 8, 256, 0, stream>>>(QKVc, 1536, KV0, KV0 + 512, 1024, Oc,
                                                1, 1, (int)(c / 128));
      gemm_h<<<dim3(4, R / 128), 256, 0, stream>>>(Oc, Wl + 1835008, ca_bo, Ac,
                                                   (int)R, 512, 512, 512, 0);
      ln_h<<<R / 4, 256, 0, stream>>>(Xsh, 0, Ac, Xh, ln2_g, ln2_b, c, 4095);
      for (long s = 0; s < R; s += Rh) {
        gemm_h<<<dim3(16, Rh / 128), 256, 0, stream>>>(Xh + (c + s) * 512, Wl + 2097152,
                                                       ffn_b1, Hb, (int)Rh, 2048, 512, 2048, 1);
        gemm_h<<<dim3(4, Rh / 128), 256, 0, stream>>>(Hb, Wl + 3145728, ffn_b2,
                                                      Ac + s * 512, (int)Rh, 512, 2048, 512, 0);
      }
      ln_h<<<R / 4, 256, 0, stream>>>(Xh, 0, Ac, Xh, ln3_g, ln3_b, c, 0x7FFFFFFF);
    }
  }
  // =================== layer 1 (x rows = 32768, chunked by R) ===================
  {
    _Float16* Wl = Wh + 4194304;
    gemm_h<<<dim3(8, 8), 256, 0, stream>>>(qh, Wl + 1310720, Bkv + 1024, KV0, 1024, 1024, 512, 1024, 0);
    for (long c = 0; c < 32768; c += R) {
      _Float16* Xhc = Xh + c * 512;
      gemm_h<<<dim3(12, R / 128), 256, 0, stream>>>(Xhc, Wl + 0, Bqkv + 1536, QKVc,
                                                    (int)R, 1536, 512, 1536, 0);
      attn_h<<<(R / 128) * 8, 256, 0, stream>>>(QKVc, 1536, QKVc + 512, QKVc + 1024, 1536,
                                                Oc, 0, 0, 0);
      gemm_h<<<dim3(4, R / 128), 256, 0, stream>>>(Oc, Wl + 786432, sa_bo + 512, Ac,
                                                   (int)R, 512, 512, 512, 0);
      ln_h<<<R / 4, 256, 0, stream>>>(Xh, 0, Ac, Xh, ln1_g + 512, ln1_b + 512, c, 0x7FFFFFFF);
      gemm_h<<<dim3(4, R / 128), 256, 0, stream>>>(Xhc, Wl + 1048576, ca_bq + 512, QKVc,
                                                   (int)R, 512, 512, 1536, 0);
      attn_h<<<(R / 128) * 8, 256, 0, stream>>>(QKVc, 1536, KV0, KV0 + 512, 1024, Oc,
                                                1, 0, (int)(c / 128));
      gemm_h<<<dim3(4, R / 128), 256, 0, stream>>>(Oc, Wl + 1835008, ca_bo + 512, Ac,
                                                   (int)R, 512, 512, 512, 0);
      ln_h<<<R / 4, 256, 0, stream>>>(Xh, 0, Ac, Xh, ln2_g + 512, ln2_b + 512, c, 0x7FFFFFFF);
      for (long s = 0; s < R; s += Rh) {
        gemm_h<<<dim3(16, Rh / 128), 256, 0, stream>>>(Xh + (c + s) * 512, Wl + 2097152,
                                                       ffn_b1 + 2048, Hb, (int)Rh, 2048, 512, 2048, 1);
        gemm_h<<<dim3(4, Rh / 128), 256, 0, stream>>>(Hb, Wl + 3145728, ffn_b2 + 512,
                                                      Ac + s * 512, (int)Rh, 512, 2048, 512, 0);
      }
      ln_h<<<R / 4, 256, 0, stream>>>(Xh, 0, Ac, Xh, ln3_g + 512, ln3_b + 512, c, 0x7FFFFFFF);
    }
  }
  // =================== final LN + pooling + features + cosine ===================
  ln_h<<<8192, 256, 0, stream>>>(Xh, 0, nullptr, Xh, lnf_g, lnf_b, 0, 0x7FFFFFFF);
  pool_h<<<256, 256, 0, stream>>>(Xh, CP);
  pool_f<<<8, 256, 0, stream>>>(q_in, QP);
  featq_kernel<<<8, 256, 0, stream>>>(QP, feat_wq, feat_bq, QN);
  featc_kernel<<<256, 256, 0, stream>>>(CP, feat_wc, feat_bc, QN, (float*)d_out);
}

// Round 7
// 1228.079 us; speedup vs baseline: 5.6235x; 1.0068x over previous
//
#include <hip/hip_runtime.h>

using half4  = __attribute__((ext_vector_type(4))) _Float16;
using half8  = __attribute__((ext_vector_type(8))) _Float16;
using floatx4 = __attribute__((ext_vector_type(4))) float;

__device__ __forceinline__ void gl_lds16(const _Float16* g, _Float16* l)
{
  __builtin_amdgcn_global_load_lds(
      (const __attribute__((address_space(1))) void*)g,
      (__attribute__((address_space(3))) void*)l, 16, 0, 0);
}

// ---------------- MFMA fp16 GEMM (128x128 tile): C = A @ Bt^T + bias
__global__ __launch_bounds__(256) void gemm_h(
    const _Float16* __restrict__ A, const _Float16* __restrict__ Bt,
    const float* __restrict__ bias, _Float16* __restrict__ C,
    int M, int N, int K, int ldC, int relu)
{
  __shared__ _Float16 As[128 * 32];
  __shared__ _Float16 Bs[128 * 32];
  int tid = threadIdx.x;
  int lane = tid & 63, wave = tid >> 6;
  long bm0 = (long)blockIdx.y * 128;
  int bn0 = blockIdx.x * 128;
  int wm = (wave & 1) * 64, wn = (wave >> 1) * 64;
  int srow = wave * 16 + (lane >> 2);
  int scol = (lane & 3) * 8;
  const _Float16* aA0 = A + (bm0 + srow) * (long)K + scol;
  const _Float16* aA1 = aA0 + 64 * (long)K;
  const _Float16* aB0 = Bt + (bn0 + srow) * (long)K + scol;
  const _Float16* aB1 = aB0 + 64 * (long)K;
  _Float16* lA0 = As + wave * 512;
  _Float16* lA1 = As + 2048 + wave * 512;
  _Float16* lB0 = Bs + wave * 512;
  _Float16* lB1 = Bs + 2048 + wave * 512;
  int mrow = lane & 15, quad = lane >> 4;
  floatx4 acc[4][4];
#pragma unroll
  for (int i = 0; i < 4; ++i)
#pragma unroll
    for (int j = 0; j < 4; ++j) acc[i][j] = (floatx4){0.f, 0.f, 0.f, 0.f};

  for (int kt = 0; kt < K; kt += 32) {
    __syncthreads();
    gl_lds16(aA0 + kt, lA0);
    gl_lds16(aA1 + kt, lA1);
    gl_lds16(aB0 + kt, lB0);
    gl_lds16(aB1 + kt, lB1);
    __syncthreads();
    half8 af[4], bf[4];
#pragma unroll
    for (int i = 0; i < 4; ++i)
      af[i] = *(const half8*)&As[(wm + 16 * i + mrow) * 32 + quad * 8];
#pragma unroll
    for (int j = 0; j < 4; ++j)
      bf[j] = *(const half8*)&Bs[(wn + 16 * j + mrow) * 32 + quad * 8];
#pragma unroll
    for (int i = 0; i < 4; ++i)
#pragma unroll
      for (int j = 0; j < 4; ++j)
        acc[i][j] = __builtin_amdgcn_mfma_f32_16x16x32_f16(af[i], bf[j], acc[i][j], 0, 0, 0);
  }
#pragma unroll
  for (int j = 0; j < 4; ++j) {
    int n = bn0 + wn + 16 * j + mrow;
    float bj = bias[n];
#pragma unroll
    for (int i = 0; i < 4; ++i) {
#pragma unroll
      for (int r = 0; r < 4; ++r) {
        long m = bm0 + wm + 16 * i + quad * 4 + r;
        float v = acc[i][j][r] + bj;
        if (relu) v = fmaxf(v, 0.f);
        C[m * (long)ldC + n] = (_Float16)v;
      }
    }
  }
}

// ---------------- MFMA fp16 GEMM (256x128 tile): 4 waves, wave = 64 rows x 128 cols.
// 12 ds_read_b128 per 32 MFMA (vs 8/16) + half the per-output fixed cost.
__global__ __launch_bounds__(256, 2) void gemm_2(
    const _Float16* __restrict__ A, const _Float16* __restrict__ Bt,
    const float* __restrict__ bias, _Float16* __restrict__ C,
    int M, int N, int K, int ldC, int relu)
{
  __shared__ _Float16 As[256 * 32];   // 16 KB
  __shared__ _Float16 Bs[128 * 32];   //  8 KB
  int tid = threadIdx.x;
  int lane = tid & 63, wave = tid >> 6;
  long bm0 = (long)blockIdx.y * 256;
  int bn0 = blockIdx.x * 128;
  int srow = lane >> 2;               // 16 rows per wave-op
  int scol = (lane & 3) * 8;
  // A: wave w stages rows [w*64, w*64+64) in 4 ops of 16 rows
  const _Float16* aA[4];
  _Float16* lA[4];
#pragma unroll
  for (int it = 0; it < 4; ++it) {
    aA[it] = A + (bm0 + wave * 64 + it * 16 + srow) * (long)K + scol;
    lA[it] = As + (wave * 64 + it * 16) * 32;
  }
  // B: op it covers rows it*64 + wave*16 + srow
  const _Float16* aB[2];
  _Float16* lB[2];
#pragma unroll
  for (int it = 0; it < 2; ++it) {
    aB[it] = Bt + (bn0 + it * 64 + wave * 16 + srow) * (long)K + scol;
    lB[it] = Bs + (it * 64 + wave * 16) * 32;
  }
  int mrow = lane & 15, quad = lane >> 4;
  floatx4 acc[4][8];
#pragma unroll
  for (int i = 0; i < 4; ++i)
#pragma unroll
    for (int j = 0; j < 8; ++j) acc[i][j] = (floatx4){0.f, 0.f, 0.f, 0.f};

  for (int kt = 0; kt < K; kt += 32) {
    __syncthreads();
#pragma unroll
    for (int it = 0; it < 4; ++it) gl_lds16(aA[it] + kt, lA[it]);
#pragma unroll
    for (int it = 0; it < 2; ++it) gl_lds16(aB[it] + kt, lB[it]);
    __syncthreads();
    half8 af[4], bf[8];
#pragma unroll
    for (int i = 0; i < 4; ++i)
      af[i] = *(const half8*)&As[(wave * 64 + 16 * i + mrow) * 32 + quad * 8];
#pragma unroll
    for (int j = 0; j < 8; ++j)
      bf[j] = *(const half8*)&Bs[(16 * j + mrow) * 32 + quad * 8];
#pragma unroll
    for (int i = 0; i < 4; ++i)
#pragma unroll
      for (int j = 0; j < 8; ++j)
        acc[i][j] = __builtin_amdgcn_mfma_f32_16x16x32_f16(af[i], bf[j], acc[i][j], 0, 0, 0);
  }
#pragma unroll
  for (int j = 0; j < 8; ++j) {
    int n = bn0 + 16 * j + mrow;
    float bj = bias[n];
#pragma unroll
    for (int i = 0; i < 4; ++i) {
#pragma unroll
      for (int r = 0; r < 4; ++r) {
        long m = bm0 + wave * 64 + 16 * i + quad * 4 + r;
        float v = acc[i][j][r] + bj;
        if (relu) v = fmaxf(v, 0.f);
        C[m * (long)ldC + n] = (_Float16)v;
      }
    }
  }
}

// ---------------- MFMA fused attention (unchanged from round 6)
__global__ __launch_bounds__(256) void attn_h(
    const _Float16* __restrict__ Qp, int qs,
    const _Float16* __restrict__ Kp, const _Float16* __restrict__ Vp, int ks,
    _Float16* __restrict__ Op, int mode_ca, int l0, int rb0)
{
  __shared__ _Float16 KV[128 * 72];
  __shared__ _Float16 Ps[128 * 136];
  int tid = threadIdx.x;
  int lane = tid & 63, wave = tid >> 6;
  int ll = lane & 15, quad = lane >> 4;
  int idx = blockIdx.x;
  int n = idx & 7;
  int rl = idx >> 3;
  long obase = (long)rl * 128 * 512 + n * 64;
  long qoff, koff;
  if (!mode_ca) {
    qoff = (long)rl * 128 * qs + n * 64;
    koff = (long)rl * 128 * ks + n * 64;
  } else {
    int g = rb0 + rl;
    int a = g >> 5;
    int qblk = l0 ? (g & 31) : rl;
    qoff = (long)qblk * 128 * qs + n * 64;
    koff = (long)a * 128 * ks + n * 64;
  }
#pragma unroll
  for (int it = 0; it < 4; ++it) {
    int e = tid + it * 256;
    int r = e >> 3, c = (e & 7) * 8;
    *(half8*)&KV[r * 72 + c] = *(const half8*)&Kp[koff + (long)r * ks + c];
  }
  half8 aQ[2][2];
#pragma unroll
  for (int i = 0; i < 2; ++i)
#pragma unroll
    for (int k2 = 0; k2 < 2; ++k2)
      aQ[i][k2] = *(const half8*)&Qp[qoff + (long)(wave * 32 + i * 16 + ll) * qs
                                     + quad * 8 + k2 * 32];
  __syncthreads();
  floatx4 accS[2][8];
#pragma unroll
  for (int i = 0; i < 2; ++i)
#pragma unroll
    for (int j = 0; j < 8; ++j) accS[i][j] = (floatx4){0.f, 0.f, 0.f, 0.f};
#pragma unroll
  for (int k2 = 0; k2 < 2; ++k2) {
#pragma unroll
    for (int j = 0; j < 8; ++j) {
      half8 bK = *(const half8*)&KV[(j * 16 + ll) * 72 + quad * 8 + k2 * 32];
      accS[0][j] = __builtin_amdgcn_mfma_f32_16x16x32_f16(aQ[0][k2], bK, accS[0][j], 0, 0, 0);
      accS[1][j] = __builtin_amdgcn_mfma_f32_16x16x32_f16(aQ[1][k2], bK, accS[1][j], 0, 0, 0);
    }
  }
  float rinv[2][4];
#pragma unroll
  for (int i = 0; i < 2; ++i) {
#pragma unroll
    for (int r = 0; r < 4; ++r) {
      float mx = -1e30f;
#pragma unroll
      for (int j = 0; j < 8; ++j) {
        accS[i][j][r] *= 0.125f;
        mx = fmaxf(mx, accS[i][j][r]);
      }
#pragma unroll
      for (int off = 1; off < 16; off <<= 1) mx = fmaxf(mx, __shfl_xor(mx, off));
      float s = 0.f;
#pragma unroll
      for (int j = 0; j < 8; ++j) {
        float e = __expf(accS[i][j][r] - mx);
        accS[i][j][r] = e;
        s += e;
      }
#pragma unroll
      for (int off = 1; off < 16; off <<= 1) s += __shfl_xor(s, off);
      rinv[i][r] = 1.f / s;
      int prow = wave * 32 + i * 16 + quad * 4 + r;
#pragma unroll
      for (int j = 0; j < 8; ++j)
        Ps[prow * 136 + j * 16 + ll] = (_Float16)accS[i][j][r];
    }
  }
  __syncthreads();
#pragma unroll
  for (int it = 0; it < 4; ++it) {
    int e = tid + it * 256;
    int vr = e >> 3, c = (e & 7) * 8;
    half8 v = *(const half8*)&Vp[koff + (long)vr * ks + c];
#pragma unroll
    for (int j = 0; j < 8; ++j) KV[(c + j) * 132 + vr] = v[j];
  }
  __syncthreads();
  floatx4 accO[2][4];
#pragma unroll
  for (int i = 0; i < 2; ++i)
#pragma unroll
    for (int j = 0; j < 4; ++j) accO[i][j] = (floatx4){0.f, 0.f, 0.f, 0.f};
#pragma unroll
  for (int k4 = 0; k4 < 4; ++k4) {
    half8 aP[2];
#pragma unroll
    for (int i = 0; i < 2; ++i)
      aP[i] = *(const half8*)&Ps[(wave * 32 + i * 16 + ll) * 136 + quad * 8 + k4 * 32];
#pragma unroll
    for (int jh = 0; jh < 4; ++jh) {
      int vb = (jh * 16 + ll) * 132 + quad * 8 + k4 * 32;
      half4 v0 = *(const half4*)&KV[vb];
      half4 v1 = *(const half4*)&KV[vb + 4];
      half8 bV = __builtin_shufflevector(v0, v1, 0, 1, 2, 3, 4, 5, 6, 7);
      accO[0][jh] = __builtin_amdgcn_mfma_f32_16x16x32_f16(aP[0], bV, accO[0][jh], 0, 0, 0);
      accO[1][jh] = __builtin_amdgcn_mfma_f32_16x16x32_f16(aP[1], bV, accO[1][jh], 0, 0, 0);
    }
  }
#pragma unroll
  for (int i = 0; i < 2; ++i)
#pragma unroll
    for (int jh = 0; jh < 4; ++jh)
#pragma unroll
      for (int r = 0; r < 4; ++r) {
        int m = wave * 32 + i * 16 + quad * 4 + r;
        Op[obase + (long)m * 512 + jh * 16 + ll] = (_Float16)(accO[i][jh][r] * rinv[i][r]);
      }
}

// ---------------- Residual + LayerNorm (rows of 512, fp32 math). One wave per row.
__global__ __launch_bounds__(256) void ln_h(
    const void* __restrict__ xin, int xf32, const _Float16* __restrict__ add,
    _Float16* __restrict__ out, const float* __restrict__ g,
    const float* __restrict__ bt, long row0, int bmask)
{
  int rl = blockIdx.x * 4 + (threadIdx.x >> 6);
  long row = row0 + rl;
  int lane = threadIdx.x & 63;
  long xr = (row & (long)bmask) * 512 + lane * 8;
  float v[8];
  if (xf32) {
    float4 a0 = *(const float4*)((const float*)xin + xr);
    float4 a1 = *(const float4*)((const float*)xin + xr + 4);
    v[0] = a0.x; v[1] = a0.y; v[2] = a0.z; v[3] = a0.w;
    v[4] = a1.x; v[5] = a1.y; v[6] = a1.z; v[7] = a1.w;
  } else {
    half8 h = *(const half8*)((const _Float16*)xin + xr);
#pragma unroll
    for (int i = 0; i < 8; ++i) v[i] = (float)h[i];
  }
  if (add) {
    half8 a = *(const half8*)&add[(long)rl * 512 + lane * 8];
#pragma unroll
    for (int i = 0; i < 8; ++i) v[i] += (float)a[i];
  }
  float s = 0.f, sq = 0.f;
#pragma unroll
  for (int i = 0; i < 8; ++i) { s += v[i]; sq += v[i] * v[i]; }
#pragma unroll
  for (int off = 1; off < 64; off <<= 1) {
    s += __shfl_xor(s, off);
    sq += __shfl_xor(sq, off);
  }
  float mean = s * (1.f / 512.f);
  float var = sq * (1.f / 512.f) - mean * mean;
  float rst = rsqrtf(var + 1e-6f);
  int c = lane * 8;
  float4 g0 = *(const float4*)&g[c], g1 = *(const float4*)&g[c + 4];
  float4 b0 = *(const float4*)&bt[c], b1 = *(const float4*)&bt[c + 4];
  float gg[8] = {g0.x, g0.y, g0.z, g0.w, g1.x, g1.y, g1.z, g1.w};
  float bb[8] = {b0.x, b0.y, b0.z, b0.w, b1.x, b1.y, b1.z, b1.w};
  half8 o;
#pragma unroll
  for (int i = 0; i < 8; ++i) o[i] = (_Float16)((v[i] - mean) * rst * gg[i] + bb[i]);
  *(half8*)&out[row * 512 + c] = o;
}

// ---------------- transpose-convert: in fp32 [Rr][Cc] -> out fp16 [Cc][Rr]
__global__ __launch_bounds__(256) void tconv(const float* __restrict__ in,
                                             _Float16* __restrict__ out, int Rr, int Cc)
{
  __shared__ float T[64][65];
  int tx = threadIdx.x & 63, tg = threadIdx.x >> 6;
  int r0 = blockIdx.y * 64, c0 = blockIdx.x * 64;
#pragma unroll
  for (int i = 0; i < 16; ++i)
    T[tg + 4 * i][tx] = in[(long)(r0 + tg + 4 * i) * Cc + c0 + tx];
  __syncthreads();
#pragma unroll
  for (int i = 0; i < 16; ++i)
    out[(long)(c0 + tg + 4 * i) * Rr + r0 + tx] = (_Float16)T[tx][tg + 4 * i];
}

// ---------------- wo layer slice (8,512,64) fp32 -> Bt[d=512][nh=512] fp16
__global__ void woconv(const float* __restrict__ wo, _Float16* __restrict__ out)
{
  int o = blockIdx.x * 256 + threadIdx.x;  // 262144
  int d = o >> 9;
  int nh = o & 511;
  int n = nh >> 6, h = nh & 63;
  out[o] = (_Float16)wo[((long)(n << 9) + d) * 64 + h];
}

__global__ void f2h(const float* __restrict__ in, _Float16* __restrict__ out, long n)
{
  long i = blockIdx.x * 256L + threadIdx.x;
  if (i < n) out[i] = (_Float16)in[i];
}

__global__ void copyf(const float* __restrict__ s, float* __restrict__ d, int n)
{
  int i = blockIdx.x * 256 + threadIdx.x;
  if (i < n) d[i] = s[i];
}

// ---------------- mean over tokens 1..127 -> [ab, 512]
__global__ void pool_h(const _Float16* __restrict__ X, float* __restrict__ P)
{
  int ab = blockIdx.x;
  for (int dd = threadIdx.x; dd < 512; dd += 256) {
    const _Float16* base = X + (long)ab * 65536 + dd;
    float s = 0.f;
    for (int t = 1; t < 128; ++t) s += (float)base[t * 512];
    P[ab * 512 + dd] = s * (1.f / 127.f);
  }
}

__global__ void pool_f(const float* __restrict__ X, float* __restrict__ P)
{
  int ab = blockIdx.x;
  for (int dd = threadIdx.x; dd < 512; dd += 256) {
    const float* base = X + (long)ab * 65536 + dd;
    float s = 0.f;
    for (int t = 1; t < 128; ++t) s += base[t * 512];
    P[ab * 512 + dd] = s * (1.f / 127.f);
  }
}

__global__ void featq_kernel(const float* __restrict__ QP, const float* __restrict__ W,
                             const float* __restrict__ bias, float* __restrict__ QN)
{
  int a = blockIdx.x;
  int f = threadIdx.x;
  float acc = bias[f];
  const float* xr = QP + a * 512;
  for (int d = 0; d < 512; ++d) acc += xr[d] * W[d * 256 + f];
  __shared__ float red[256];
  red[f] = acc * acc;
  __syncthreads();
  for (int s = 128; s > 0; s >>= 1) {
    if (f < s) red[f] += red[f + s];
    __syncthreads();
  }
  float rn = rsqrtf(fmaxf(red[0], 1e-12f));
  QN[a * 256 + f] = acc * rn;
}

__global__ void featc_kernel(const float* __restrict__ CP, const float* __restrict__ W,
                             const float* __restrict__ bias, const float* __restrict__ QN,
                             float* __restrict__ out)
{
  int ab = blockIdx.x;
  int f = threadIdx.x;
  float acc = bias[f];
  const float* xr = CP + ab * 512;
  for (int d = 0; d < 512; ++d) acc += xr[d] * W[d * 256 + f];
  __shared__ float red[256];
  red[f] = acc * acc;
  __syncthreads();
  for (int s = 128; s > 0; s >>= 1) {
    if (f < s) red[f] += red[f + s];
    __syncthreads();
  }
  float rn = rsqrtf(fmaxf(red[0], 1e-12f));
  float v = acc * rn * QN[(ab >> 5) * 256 + f];
  __syncthreads();
  red[f] = v;
  __syncthreads();
  for (int s = 128; s > 0; s >>= 1) {
    if (f < s) red[f] += red[f + s];
    __syncthreads();
  }
  if (f == 0) out[ab] = red[0];
}

extern "C" void kernel_launch(void* const* d_in, const int* in_sizes, int n_in,
                              void* d_out, int out_size, void* d_ws, size_t ws_size,
                              hipStream_t stream)
{
  (void)in_sizes; (void)n_in; (void)out_size;
  const float* c_in  = (const float*)d_in[0];
  const float* q_in  = (const float*)d_in[1];
  const float* sa_wq = (const float*)d_in[2];
  const float* sa_bq = (const float*)d_in[3];
  const float* sa_wk = (const float*)d_in[4];
  const float* sa_bk = (const float*)d_in[5];
  const float* sa_wv = (const float*)d_in[6];
  const float* sa_bv = (const float*)d_in[7];
  const float* sa_wo = (const float*)d_in[8];
  const float* sa_bo = (const float*)d_in[9];
  const float* ca_wq = (const float*)d_in[10];
  const float* ca_bq = (const float*)d_in[11];
  const float* ca_wk = (const float*)d_in[12];
  const float* ca_bk = (const float*)d_in[13];
  const float* ca_wv = (const float*)d_in[14];
  const float* ca_bv = (const float*)d_in[15];
  const float* ca_wo = (const float*)d_in[16];
  const float* ca_bo = (const float*)d_in[17];
  const float* ln1_g = (const float*)d_in[18];
  const float* ln1_b = (const float*)d_in[19];
  const float* ln2_g = (const float*)d_in[20];
  const float* ln2_b = (const float*)d_in[21];
  const float* ln3_g = (const float*)d_in[22];
  const float* ln3_b = (const float*)d_in[23];
  const float* ffn_w1 = (const float*)d_in[24];
  const float* ffn_b1 = (const float*)d_in[25];
  const float* ffn_w2 = (const float*)d_in[26];
  const float* ffn_b2 = (const float*)d_in[27];
  const float* lnf_g  = (const float*)d_in[28];
  const float* lnf_b  = (const float*)d_in[29];
  const float* feat_wq = (const float*)d_in[30];
  const float* feat_bq = (const float*)d_in[31];
  const float* feat_wc = (const float*)d_in[32];
  const float* feat_bc = (const float*)d_in[33];

  // ---- workspace layout, fp16 residual stream; ws-adaptive chunk R
  char* p = (char*)d_ws;
  _Float16* Xh  = (_Float16*)p;  p += 33554432;  // 32768 x 512 fp16 residual stream
  _Float16* Xsh = (_Float16*)p;  p += 4194304;   //  4096 x 512 fp16 (layer-0 x)
  _Float16* Wh  = (_Float16*)p;  p += 16777216;  // fused fp16 weight arena (2 layers)
  _Float16* qh  = (_Float16*)p;  p += 1048576;   //  1024 x 512 fp16
  _Float16* KV0 = (_Float16*)p;  p += 2097152;   //  1024 x 1024 fp16 (K|V parts)
  float*    Bqkv = (float*)p;    p += 12288;     // 2 x 1536 packed QKV bias
  float*    Bkv  = (float*)p;    p += 8192;      // 2 x 1024 packed CA-KV bias
  float*    CP  = (float*)p;     p += 524288;
  float*    QP  = (float*)p;     p += 16384;
  float*    QN  = (float*)p;     p += 8192;
  const size_t fixed_b = (size_t)(p - (char*)d_ws);
  long R = 4096;
  if (ws_size >= fixed_b + 5120UL * 32768) R = 32768;
  else if (ws_size >= fixed_b + 5120UL * 16384) R = 16384;
  else if (ws_size >= fixed_b + 5120UL * 8192) R = 8192;
  _Float16* QKVc = (_Float16*)p; p += R * 3072;  // [R][1536] Q|K|V
  _Float16* Oc   = (_Float16*)p; p += R * 1024;  // [R][512]
  _Float16* Ac   = (_Float16*)p;                 // [R][512] residual-add input
  _Float16* Hb = QKVc;           // FFN hidden [R/2][2048] aliases QKVc
  const long Rh = R / 2;

  // ---- prep
  f2h<<<8192, 256, 0, stream>>>(c_in, Xsh, 2097152);
  f2h<<<2048, 256, 0, stream>>>(q_in, qh, 524288);
  for (int l = 0; l < 2; ++l) {
    _Float16* Wl = Wh + (long)l * 4194304;
    long woff = (long)l * 262144;
    tconv<<<dim3(8, 8), 256, 0, stream>>>(sa_wq + woff, Wl + 0, 512, 512);
    tconv<<<dim3(8, 8), 256, 0, stream>>>(sa_wk + woff, Wl + 262144, 512, 512);
    tconv<<<dim3(8, 8), 256, 0, stream>>>(sa_wv + woff, Wl + 524288, 512, 512);
    woconv<<<1024, 256, 0, stream>>>(sa_wo + woff, Wl + 786432);
    tconv<<<dim3(8, 8), 256, 0, stream>>>(ca_wq + woff, Wl + 1048576, 512, 512);
    tconv<<<dim3(8, 8), 256, 0, stream>>>(ca_wk + woff, Wl + 1310720, 512, 512);
    tconv<<<dim3(8, 8), 256, 0, stream>>>(ca_wv + woff, Wl + 1572864, 512, 512);
    woconv<<<1024, 256, 0, stream>>>(ca_wo + woff, Wl + 1835008);
    tconv<<<dim3(32, 8), 256, 0, stream>>>(ffn_w1 + (long)l * 1048576, Wl + 2097152, 512, 2048);
    tconv<<<dim3(8, 32), 256, 0, stream>>>(ffn_w2 + (long)l * 1048576, Wl + 3145728, 2048, 512);
    copyf<<<2, 256, 0, stream>>>(sa_bq + l * 512, Bqkv + l * 1536, 512);
    copyf<<<2, 256, 0, stream>>>(sa_bk + l * 512, Bqkv + l * 1536 + 512, 512);
    copyf<<<2, 256, 0, stream>>>(sa_bv + l * 512, Bqkv + l * 1536 + 1024, 512);
    copyf<<<2, 256, 0, stream>>>(ca_bk + l * 512, Bkv + l * 1024, 512);
    copyf<<<2, 256, 0, stream>>>(ca_bv + l * 512, Bkv + l * 1024 + 512, 512);
  }

  // =================== layer 0 (x rows = 4096) ===================
  {
    _Float16* Wl = Wh;
    gemm_h<<<dim3(12, 32), 256, 0, stream>>>(Xsh, Wl + 0, Bqkv, QKVc, 4096, 1536, 512, 1536, 0);
    attn_h<<<256, 256, 0, stream>>>(QKVc, 1536, QKVc + 512, QKVc + 1024, 1536, Oc, 0, 0, 0);
    gemm_h<<<dim3(4, 32), 256, 0, stream>>>(Oc, Wl + 786432, sa_bo, Ac, 4096, 512, 512, 512, 0);
    ln_h<<<1024, 256, 0, stream>>>(c_in, 1, Ac, Xsh, ln1_g, ln1_b, 0, 0x7FFFFFFF);
    gemm_h<<<dim3(4, 32), 256, 0, stream>>>(Xsh, Wl + 1048576, ca_bq, QKVc, 4096, 512, 512, 1536, 0);
    gemm_h<<<dim3(8, 8), 256, 0, stream>>>(qh, Wl + 1310720, Bkv, KV0, 1024, 1024, 512, 1024, 0);
    for (long c = 0; c < 32768; c += R) {
      attn_h<<<(R / 128) * 8, 256, 0, stream>>>(QKVc, 1536, KV0, KV0 + 512, 1024, Oc,
                                                1, 1, (int)(c / 128));
      gemm_2<<<dim3(4, R / 256), 256, 0, stream>>>(Oc, Wl + 1835008, ca_bo, Ac,
                                                   (int)R, 512, 512, 512, 0);
      ln_h<<<R / 4, 256, 0, stream>>>(Xsh, 0, Ac, Xh, ln2_g, ln2_b, c, 4095);
      for (long s = 0; s < R; s += Rh) {
        gemm_2<<<dim3(16, Rh / 256), 256, 0, stream>>>(Xh + (c + s) * 512, Wl + 2097152,
                                                       ffn_b1, Hb, (int)Rh, 2048, 512, 2048, 1);
        gemm_2<<<dim3(4, Rh / 256), 256, 0, stream>>>(Hb, Wl + 3145728, ffn_b2,
                                                      Ac + s * 512, (int)Rh, 512, 2048, 512, 0);
      }
      ln_h<<<R / 4, 256, 0, stream>>>(Xh, 0, Ac, Xh, ln3_g, ln3_b, c, 0x7FFFFFFF);
    }
  }
  // =================== layer 1 (x rows = 32768, chunked by R) ===================
  {
    _Float16* Wl = Wh + 4194304;
    gemm_h<<<dim3(8, 8), 256, 0, stream>>>(qh, Wl + 1310720, Bkv + 1024, KV0, 1024, 1024, 512, 1024, 0);
    for (long c = 0; c < 32768; c += R) {
      _Float16* Xhc = Xh + c * 512;
      gemm_2<<<dim3(12, R / 256), 256, 0, stream>>>(Xhc, Wl + 0, Bqkv + 1536, QKVc,
                                                    (int)R, 1536, 512, 1536, 0);
      attn_h<<<(R / 128) * 8, 256, 0, stream>>>(QKVc, 1536, QKVc + 512, QKVc + 1024, 1536,
                                                Oc, 0, 0, 0);
      gemm_2<<<dim3(4, R / 256), 256, 0, stream>>>(Oc, Wl + 786432, sa_bo + 512, Ac,
                                                   (int)R, 512, 512, 512, 0);
      ln_h<<<R / 4, 256, 0, stream>>>(Xh, 0, Ac, Xh, ln1_g + 512, ln1_b + 512, c, 0x7FFFFFFF);
      gemm_2<<<dim3(4, R / 256), 256, 0, stream>>>(Xhc, Wl + 1048576, ca_bq + 512, QKVc,
                                                   (int)R, 512, 512, 1536, 0);
      attn_h<<<(R / 128) * 8, 256, 0, stream>>>(QKVc, 1536, KV0, KV0 + 512, 1024, Oc,
                                                1, 0, (int)(c / 128));
      gemm_2<<<dim3(4, R / 256), 256, 0, stream>>>(Oc, Wl + 1835008, ca_bo + 512, Ac,
                                                   (int)R, 512, 512, 512, 0);
      ln_h<<<R / 4, 256, 0, stream>>>(Xh, 0, Ac, Xh, ln2_g + 512, ln2_b + 512, c, 0x7FFFFFFF);
      for (long s = 0; s < R; s += Rh) {
        gemm_2<<<dim3(16, Rh / 256), 256, 0, stream>>>(Xh + (c + s) * 512, Wl + 2097152,
                                                       ffn_b1 + 2048, Hb, (int)Rh, 2048, 512, 2048, 1);
        gemm_2<<<dim3(4, Rh / 256), 256, 0, stream>>>(Hb, Wl + 3145728, ffn_b2 + 512,
                                                      Ac + s * 512, (int)Rh, 512, 2048, 512, 0);
      }
      ln_h<<<R / 4, 256, 0, stream>>>(Xh, 0, Ac, Xh, ln3_g + 512, ln3_b + 512, c, 0x7FFFFFFF);
    }
  }
  // =================== final LN + pooling + features + cosine ===================
  ln_h<<<8192, 256, 0, stream>>>(Xh, 0, nullptr, Xh, lnf_g, lnf_b, 0, 0x7FFFFFFF);
  pool_h<<<256, 256, 0, stream>>>(Xh, CP);
  pool_f<<<8, 256, 0, stream>>>(q_in, QP);
  featq_kernel<<<8, 256, 0, stream>>>(QP, feat_wq, feat_bq, QN);
  featc_kernel<<<256, 256, 0, stream>>>(CP, feat_wc, feat_bc, QN, (float*)d_out);
}